// Round 1
// baseline (977.342 us; speedup 1.0000x reference)
//
#include <hip/hip_runtime.h>
#include <hip/hip_bf16.h>

// Problem constants
#define NB      4      // batch
#define NPERA   256    // atoms per type
#define NNEI    128    // neighbors per j-block
#define FH      240
#define FIT_IN  1600

__device__ __forceinline__ float fast_tanh(float x) {
    // tanh(x) = 1 - 2/(exp(2x)+1); exp via v_exp_f32 (2^y), rcp via v_rcp_f32
    float e2 = __builtin_amdgcn_exp2f(x * 2.8853900817779268f);
    return 1.0f - 2.0f * __builtin_amdgcn_rcpf(e2 + 1.0f);
}

// ---------------------------------------------------------------------------
// K1: embedding net + neighbor reduction + DR, one block per (b,i,n) atom.
// DRws layout: [type i][b*256+n][1600]
// ---------------------------------------------------------------------------
__global__ __launch_bounds__(256) void k_emb(
    const float* __restrict__ Ri,
    const float* __restrict__ eW0, const float* __restrict__ eB0,
    const float* __restrict__ eW1, const float* __restrict__ eB1,
    const float* __restrict__ eW2, const float* __restrict__ eB2,
    float* __restrict__ DRws)
{
    __shared__ float4 sR[128];
    __shared__ float sW0[25], sB0[25];
    __shared__ float sW1[1250], sB1[50];
    __shared__ float sW2[5000], sB2[100];
    __shared__ __hip_bfloat16 sG[128 * 102];   // stride 102 -> odd dword stride
    __shared__ float sXyz[400];                // [c][g] fp32 accumulator

    const int t   = threadIdx.x;
    const int blk = blockIdx.x;          // 0..2047
    const int b   = blk >> 9;
    const int i   = (blk >> 8) & 1;
    const int n   = blk & 255;

    for (int idx = t; idx < 400; idx += 256) sXyz[idx] = 0.f;

    const size_t riAtom = ((size_t)(b * 512 + i * 256 + n)) * 256;

    for (int j = 0; j < 2; ++j) {
        const int e = i * 2 + j;
        // stage weights (coalesced; broadcast-read later)
        for (int idx = t; idx < 1250; idx += 256) sW1[idx] = eW1[e * 1250 + idx];
        for (int idx = t; idx < 5000; idx += 256) sW2[idx] = eW2[e * 5000 + idx];
        if (t < 25)       { sW0[t] = eW0[e * 25 + t]; sB0[t] = eB0[e * 25 + t]; }
        else if (t < 75)  { sB1[t - 25] = eB1[e * 50 + (t - 25)]; }
        else if (t < 175) { sB2[t - 75] = eB2[e * 100 + (t - 75)]; }
        if (t < 128) sR[t] = *(const float4*)(Ri + (riAtom + (size_t)j * 128 + t) * 4);
        __syncthreads();

        // embedding chain: thread pair (t, t+128) shares neighbor m, splits h2
        const int m     = t & 127;
        const int gbase = (t >> 7) * 50;
        const float4 Rm = sR[m];
        const float  S  = Rm.x;

        float h0[25];
        #pragma unroll
        for (int k = 0; k < 25; ++k) h0[k] = fast_tanh(S * sW0[k] + sB0[k]);

        float h1[50];
        #pragma unroll
        for (int g = 0; g < 50; ++g) {
            float acc = sB1[g];
            #pragma unroll
            for (int k = 0; k < 25; ++k) acc += h0[k] * sW1[k * 50 + g];
            h1[g] = fast_tanh(acc) + h0[(g < 25) ? g : (g - 25)];
        }

        #pragma unroll
        for (int gi = 0; gi < 50; ++gi) {
            const int g = gbase + gi;
            float acc = sB2[g];
            #pragma unroll
            for (int k = 0; k < 50; ++k) acc += h1[k] * sW2[k * 100 + g];
            sG[m * 102 + g] = __float2bfloat16(fast_tanh(acc) + h1[gi]);
        }
        __syncthreads();

        // reduce: xyz[c][g] += sum_m R[m][c] * G[m][g]
        if (t < 100) {
            const int g = t;
            float a0 = 0.f, a1 = 0.f, a2 = 0.f, a3 = 0.f;
            #pragma unroll 4
            for (int mm = 0; mm < 128; ++mm) {
                const float Gv = __bfloat162float(sG[mm * 102 + g]);
                const float4 R = sR[mm];
                a0 += R.x * Gv; a1 += R.y * Gv; a2 += R.z * Gv; a3 += R.w * Gv;
            }
            sXyz[g]       += a0;
            sXyz[100 + g] += a1;
            sXyz[200 + g] += a2;
            sXyz[300 + g] += a3;
        }
        __syncthreads();
    }

    // DR[g][h] = (xyz[c][g]/256)*(xyz[c][h]/256) summed over c, h<16
    const float inv = 1.0f / 65536.0f;
    float* dr = DRws + (((size_t)i * 4 + b) * 256 + n) * FIT_IN;
    for (int idx = t; idx < FIT_IN; idx += 256) {
        const int g = idx >> 4, h = idx & 15;
        const float v = sXyz[g] * sXyz[h] + sXyz[100 + g] * sXyz[100 + h]
                      + sXyz[200 + g] * sXyz[200 + h] + sXyz[300 + g] * sXyz[300 + h];
        dr[idx] = v * inv;
    }
}

// ---------------------------------------------------------------------------
// K2/K3: fit layer GEMM: Out = tanh(A @ W + bias) [+ A if RES]
// A: [2][1024][K], W: [2][K][240], Out: [2][1024][240]
// grid: (4 n-tiles of 64, 32 m-tiles of 32, 2 types), 256 threads
// ---------------------------------------------------------------------------
template<int K, bool RES>
__global__ __launch_bounds__(256) void k_fit(
    const float* __restrict__ A, const float* __restrict__ W,
    const float* __restrict__ Bias, float* __restrict__ Out)
{
    __shared__ float sA[16][33];
    __shared__ float sB[16][64];
    const int t  = threadIdx.x;
    const int nt = blockIdx.x, mt = blockIdx.y, tp = blockIdx.z;
    const int n0 = nt * 64, m0 = mt * 32;
    const int tx = t & 15, ty = t >> 4;
    float acc[2][4] = {};
    const float* Ablk = A + ((size_t)tp * 1024 + m0) * K;
    const float* Wblk = W + (size_t)tp * K * 240;

    for (int k0 = 0; k0 < K; k0 += 16) {
        for (int idx = t; idx < 512; idx += 256) {
            const int kk = idx & 15, row = idx >> 4;
            sA[kk][row] = Ablk[(size_t)row * K + k0 + kk];
        }
        for (int idx = t; idx < 1024; idx += 256) {
            const int col = idx & 63, kk = idx >> 6;
            const int c = n0 + col;
            sB[kk][col] = (c < FH) ? Wblk[(size_t)(k0 + kk) * FH + c] : 0.f;
        }
        __syncthreads();
        #pragma unroll
        for (int kk = 0; kk < 16; ++kk) {
            const float a0 = sA[kk][ty * 2], a1 = sA[kk][ty * 2 + 1];
            const float b0 = sB[kk][tx * 4 + 0], b1 = sB[kk][tx * 4 + 1];
            const float b2 = sB[kk][tx * 4 + 2], b3 = sB[kk][tx * 4 + 3];
            acc[0][0] += a0 * b0; acc[0][1] += a0 * b1; acc[0][2] += a0 * b2; acc[0][3] += a0 * b3;
            acc[1][0] += a1 * b0; acc[1][1] += a1 * b1; acc[1][2] += a1 * b2; acc[1][3] += a1 * b3;
        }
        __syncthreads();
    }

    #pragma unroll
    for (int ii = 0; ii < 2; ++ii) {
        const int row = m0 + ty * 2 + ii;
        #pragma unroll
        for (int jj = 0; jj < 4; ++jj) {
            const int col = n0 + tx * 4 + jj;
            if (col < FH) {
                float v = fast_tanh(acc[ii][jj] + Bias[tp * FH + col]);
                if (RES) v += A[((size_t)tp * 1024 + row) * K + col];
                Out[((size_t)tp * 1024 + row) * FH + col] = v;
            }
        }
    }
}

// ---------------------------------------------------------------------------
// K4: final layer, one wave per atom: out = h . W3 + b3
// Hin: [2][1024][240], out: [B][512] with out[b*512 + tp*256 + n]
// ---------------------------------------------------------------------------
__global__ __launch_bounds__(256) void k_out(
    const float* __restrict__ Hin, const float* __restrict__ W3,
    const float* __restrict__ b3, float* __restrict__ out)
{
    const int wave = (int)((blockIdx.x * 256 + threadIdx.x) >> 6); // 0..2047
    const int lane = threadIdx.x & 63;
    const int tp = wave >> 10;
    const int rem = wave & 1023;
    const int b = rem >> 8, n = rem & 255;
    const float* h = Hin + (size_t)wave * FH;
    const float* w = W3 + tp * FH;
    float s = 0.f;
    for (int k = lane; k < FH; k += 64) s += h[k] * w[k];
    #pragma unroll
    for (int off = 32; off > 0; off >>= 1) s += __shfl_down(s, off);
    if (lane == 0) out[b * 512 + tp * 256 + n] = s + b3[tp];
}

// ---------------------------------------------------------------------------
extern "C" void kernel_launch(void* const* d_in, const int* in_sizes, int n_in,
                              void* d_out, int out_size, void* d_ws, size_t ws_size,
                              hipStream_t stream)
{
    const float* Ri  = (const float*)d_in[0];
    const float* eW0 = (const float*)d_in[1];
    const float* eB0 = (const float*)d_in[2];
    const float* eW1 = (const float*)d_in[3];
    const float* eB1 = (const float*)d_in[4];
    const float* eW2 = (const float*)d_in[5];
    const float* eB2 = (const float*)d_in[6];
    const float* fW0 = (const float*)d_in[7];
    const float* fb0 = (const float*)d_in[8];
    const float* fW1 = (const float*)d_in[9];
    const float* fb1 = (const float*)d_in[10];
    const float* fW2 = (const float*)d_in[11];
    const float* fb2 = (const float*)d_in[12];
    const float* fW3 = (const float*)d_in[13];
    const float* fb3 = (const float*)d_in[14];

    float* DR = (float*)d_ws;                      // 2*1024*1600 fp32 = 13.1 MB
    float* hA = DR + (size_t)2 * 1024 * FIT_IN;    // 2*1024*240 fp32
    float* hB = hA + (size_t)2 * 1024 * FH;        // 2*1024*240 fp32

    k_emb<<<dim3(2048), dim3(256), 0, stream>>>(Ri, eW0, eB0, eW1, eB1, eW2, eB2, DR);
    k_fit<FIT_IN, false><<<dim3(4, 32, 2), dim3(256), 0, stream>>>(DR, fW0, fb0, hA);
    k_fit<FH, true><<<dim3(4, 32, 2), dim3(256), 0, stream>>>(hA, fW1, fb1, hB);
    k_fit<FH, true><<<dim3(4, 32, 2), dim3(256), 0, stream>>>(hB, fW2, fb2, hA);
    k_out<<<dim3(512), dim3(256), 0, stream>>>(hA, fW3, fb3, (float*)d_out);
}

// Round 2
// 630.998 us; speedup vs baseline: 1.5489x; 1.5489x over previous
//
#include <hip/hip_runtime.h>
#include <hip/hip_bf16.h>

#define FH 240
#define FIT_IN 1600

__device__ __forceinline__ float fast_tanh(float x) {
    float e2 = __builtin_amdgcn_exp2f(x * 2.8853900817779268f);
    return 1.0f - 2.0f * __builtin_amdgcn_rcpf(e2 + 1.0f);
}

// ---------------------------------------------------------------------------
// k_emb: one block per atom (b,i,n). 256 threads = 4 waves.
// Layers 2/3 of the embedding net are LDS-tiled fp32 GEMMs with 4x8 register
// tiles; the neighbor reduction xyz[c][g] = sum_m R[m][c] G[m][g] is folded
// into the GEMM2 epilogue (register partials + shfl over the m-lane axis).
// ---------------------------------------------------------------------------
// LDS float offsets (all multiples of 4 for b128 alignment)
#define OFF_R    0      // 128 x float4 = 512
#define OFF_W0   512    // 25 (pad 28)
#define OFF_B0   540    // 25 (pad 28)
#define OFF_B1   568    // 50 (pad 52)
#define OFF_B2   620    // 100
#define OFF_W1   720    // 25 x 52 = 1300  (stride 52)
#define OFF_W2H  2020   // 50 x 52 = 2600  (stride 52, half of W2)
#define OFF_H0T  4620   // 25 x 132 = 3300 (stride 132, [k][m])
#define OFF_H1T  7920   // 50 x 132 = 6600 (stride 132, [k][m])
#define OFF_XYZ  14520  // 400
#define SMEM_F   14920  // 59680 bytes -> 2 blocks/CU

__global__ __launch_bounds__(256) void k_emb(
    const float* __restrict__ Ri,
    const float* __restrict__ eW0, const float* __restrict__ eB0,
    const float* __restrict__ eW1, const float* __restrict__ eB1,
    const float* __restrict__ eW2, const float* __restrict__ eB2,
    float* __restrict__ DRws)
{
    __shared__ float sm[SMEM_F];

    const int t    = threadIdx.x;
    const int w    = t >> 6;
    const int lane = t & 63;
    const int mi   = lane >> 3;       // 0..7 (m-lane axis)
    const int gi   = lane & 7;        // 0..7 (g-lane axis)
    const int mrow = w * 32 + mi * 4; // lane's first m row (0..124)

    const int blk = blockIdx.x;       // 0..2047
    const int b   = blk >> 9;
    const int i   = (blk >> 8) & 1;
    const int n   = blk & 255;

    for (int idx = t; idx < 400; idx += 256) sm[OFF_XYZ + idx] = 0.f;

    float partial[4][16];             // [c][half*8 + gcol]
    #pragma unroll
    for (int c = 0; c < 4; ++c)
        #pragma unroll
        for (int q = 0; q < 16; ++q) partial[c][q] = 0.f;

    const size_t riAtom = ((size_t)(b * 512 + i * 256 + n)) * 256;

    for (int j = 0; j < 2; ++j) {
        const int e = i * 2 + j;
        __syncthreads();  // prior-phase readers done before restage

        // ---- stage W0/b0/W1/b1/b2 and R ----
        for (int idx = t; idx < 1250; idx += 256) {
            int k = idx / 50, g = idx - k * 50;
            sm[OFF_W1 + k * 52 + g] = eW1[e * 1250 + idx];
        }
        if (t < 25)       { sm[OFF_W0 + t] = eW0[e * 25 + t]; sm[OFF_B0 + t] = eB0[e * 25 + t]; }
        else if (t < 75)  { sm[OFF_B1 + (t - 25)] = eB1[e * 50 + (t - 25)]; }
        else if (t < 175) { sm[OFF_B2 + (t - 75)] = eB2[e * 100 + (t - 75)]; }
        if (t < 128) {
            float4 r = *(const float4*)(Ri + (riAtom + (size_t)j * 128 + t) * 4);
            *(float4*)&sm[OFF_R + t * 4] = r;
        }
        __syncthreads();

        // ---- layer 1: h0[k] per neighbor, store transposed [k][m] ----
        if (t < 128) {
            const float S = sm[OFF_R + t * 4];
            #pragma unroll
            for (int k = 0; k < 25; ++k) {
                sm[OFF_H0T + k * 132 + t] = fast_tanh(S * sm[OFF_W0 + k] + sm[OFF_B0 + k]);
            }
        }
        __syncthreads();

        // ---- GEMM1: h1pre[m][g] = sum_k h0T[k][m] * W1[k][g]  (M=128,N=50,K=25)
        {
            float acc[4][8];
            #pragma unroll
            for (int r = 0; r < 4; ++r)
                #pragma unroll
                for (int c = 0; c < 8; ++c) acc[r][c] = 0.f;

            #pragma unroll 5
            for (int k = 0; k < 25; ++k) {
                const float4 a  = *(const float4*)&sm[OFF_H0T + k * 132 + mrow];
                const float4 b0 = *(const float4*)&sm[OFF_W1 + k * 52 + gi * 8];
                const float4 b1 = *(const float4*)&sm[OFF_W1 + k * 52 + gi * 8 + 4];
                #define FMA_ROW(r, av) \
                    acc[r][0] += (av) * b0.x; acc[r][1] += (av) * b0.y; \
                    acc[r][2] += (av) * b0.z; acc[r][3] += (av) * b0.w; \
                    acc[r][4] += (av) * b1.x; acc[r][5] += (av) * b1.y; \
                    acc[r][6] += (av) * b1.z; acc[r][7] += (av) * b1.w;
                FMA_ROW(0, a.x) FMA_ROW(1, a.y) FMA_ROW(2, a.z) FMA_ROW(3, a.w)
            }
            // epilogue: h1 = tanh(acc + b1) + h0[g mod 25], store transposed
            #pragma unroll
            for (int c = 0; c < 8; ++c) {
                const int g = gi * 8 + c;
                if (g < 50) {
                    const int gm = (g < 25) ? g : g - 25;
                    const float4 h0r = *(const float4*)&sm[OFF_H0T + gm * 132 + mrow];
                    const float bias = sm[OFF_B1 + g];
                    float4 o;
                    o.x = fast_tanh(acc[0][c] + bias) + h0r.x;
                    o.y = fast_tanh(acc[1][c] + bias) + h0r.y;
                    o.z = fast_tanh(acc[2][c] + bias) + h0r.z;
                    o.w = fast_tanh(acc[3][c] + bias) + h0r.w;
                    *(float4*)&sm[OFF_H1T + g * 132 + mrow] = o;
                }
            }
        }

        // ---- GEMM2 in two 50-col halves: G = tanh(h1@W2+b2)+h1, fused reduce
        for (int half = 0; half < 2; ++half) {
            __syncthreads();  // H1T complete / prior-half readers done
            for (int idx = t; idx < 2500; idx += 256) {
                int k = idx / 50, g = idx - k * 50;
                sm[OFF_W2H + k * 52 + g] = eW2[e * 5000 + k * 100 + half * 50 + g];
            }
            __syncthreads();

            float acc[4][8];
            #pragma unroll
            for (int r = 0; r < 4; ++r)
                #pragma unroll
                for (int c = 0; c < 8; ++c) acc[r][c] = 0.f;

            #pragma unroll 5
            for (int k = 0; k < 50; ++k) {
                const float4 a  = *(const float4*)&sm[OFF_H1T + k * 132 + mrow];
                const float4 b0 = *(const float4*)&sm[OFF_W2H + k * 52 + gi * 8];
                const float4 b1 = *(const float4*)&sm[OFF_W2H + k * 52 + gi * 8 + 4];
                FMA_ROW(0, a.x) FMA_ROW(1, a.y) FMA_ROW(2, a.z) FMA_ROW(3, a.w)
            }

            // epilogue: G then partial[c][g] += R[m][c]*G[m][g] over lane's 4 m
            const float4 Rv0 = *(const float4*)&sm[OFF_R + (mrow + 0) * 4];
            const float4 Rv1 = *(const float4*)&sm[OFF_R + (mrow + 1) * 4];
            const float4 Rv2 = *(const float4*)&sm[OFF_R + (mrow + 2) * 4];
            const float4 Rv3 = *(const float4*)&sm[OFF_R + (mrow + 3) * 4];
            #pragma unroll
            for (int c = 0; c < 8; ++c) {
                const int g  = gi * 8 + c;
                const int gq = (g < 50) ? g : 49;   // clamp: keep LDS reads in-bounds
                const float4 h1r = *(const float4*)&sm[OFF_H1T + gq * 132 + mrow];
                const float bias = sm[OFF_B2 + half * 50 + gq];
                const float g0 = fast_tanh(acc[0][c] + bias) + h1r.x;
                const float g1 = fast_tanh(acc[1][c] + bias) + h1r.y;
                const float g2 = fast_tanh(acc[2][c] + bias) + h1r.z;
                const float g3 = fast_tanh(acc[3][c] + bias) + h1r.w;
                const int q = half * 8 + c;
                partial[0][q] += Rv0.x * g0 + Rv1.x * g1 + Rv2.x * g2 + Rv3.x * g3;
                partial[1][q] += Rv0.y * g0 + Rv1.y * g1 + Rv2.y * g2 + Rv3.y * g3;
                partial[2][q] += Rv0.z * g0 + Rv1.z * g1 + Rv2.z * g2 + Rv3.z * g3;
                partial[3][q] += Rv0.w * g0 + Rv1.w * g1 + Rv2.w * g2 + Rv3.w * g3;
            }
        }
    }

    // ---- reduce partials: shfl over mi axis (lane bits 3..5), then LDS ----
    #pragma unroll
    for (int cc = 0; cc < 4; ++cc)
        #pragma unroll
        for (int q = 0; q < 16; ++q) {
            float v = partial[cc][q];
            v += __shfl_xor(v, 8, 64);
            v += __shfl_xor(v, 16, 64);
            v += __shfl_xor(v, 32, 64);
            partial[cc][q] = v;
        }
    if (mi == 0) {
        #pragma unroll
        for (int cc = 0; cc < 4; ++cc)
            #pragma unroll
            for (int q = 0; q < 16; ++q) {
                const int half = q >> 3, c = q & 7;
                const int g = gi * 8 + c;
                if (g < 50)
                    atomicAdd(&sm[OFF_XYZ + cc * 100 + half * 50 + g], partial[cc][q]);
            }
    }
    __syncthreads();

    // ---- DR[g][h] = sum_c (xyz[c][g]/256)(xyz[c][h]/256), h<16 ----
    const float inv = 1.0f / 65536.0f;
    float* dr = DRws + (((size_t)i * 4 + b) * 256 + n) * FIT_IN;
    for (int idx = t; idx < FIT_IN; idx += 256) {
        const int g = idx >> 4, h = idx & 15;
        const float v = sm[OFF_XYZ + g] * sm[OFF_XYZ + h]
                      + sm[OFF_XYZ + 100 + g] * sm[OFF_XYZ + 100 + h]
                      + sm[OFF_XYZ + 200 + g] * sm[OFF_XYZ + 200 + h]
                      + sm[OFF_XYZ + 300 + g] * sm[OFF_XYZ + 300 + h];
        dr[idx] = v * inv;
    }
}

// ---------------------------------------------------------------------------
// k_fit: Out = tanh(A@W + bias) [+ A if RES].  A:[2][1024][K]  W:[2][K][240]
// 64x64 block tile, 4x4 per-lane register tile, K-chunk 32, b128 B-reads.
// grid (4 n-tiles, 16 m-tiles, 2 types), 256 threads.
// ---------------------------------------------------------------------------
template<int K, bool RES>
__global__ __launch_bounds__(256) void k_fit(
    const float* __restrict__ A, const float* __restrict__ W,
    const float* __restrict__ Bias, float* __restrict__ Out)
{
    __shared__ float sA[64 * 36];   // [m][kk], stride 36
    __shared__ float sB[32 * 68];   // [kk][n], stride 68

    const int t  = threadIdx.x;
    const int tx = t & 15, ty = t >> 4;
    const int n0 = blockIdx.x * 64, m0 = blockIdx.y * 64;
    const int tp = blockIdx.z;

    const float* Ablk = A + ((size_t)tp * 1024 + m0) * K;
    const float* Wblk = W + (size_t)tp * K * FH;

    float acc[4][4];
    #pragma unroll
    for (int r = 0; r < 4; ++r)
        #pragma unroll
        for (int c = 0; c < 4; ++c) acc[r][c] = 0.f;

    for (int k0 = 0; k0 < K; k0 += 32) {
        for (int idx = t; idx < 2048; idx += 256) {
            const int kk = idx & 31, m = idx >> 5;
            const int k = k0 + kk;
            sA[m * 36 + kk] = (k < K) ? Ablk[(size_t)m * K + k] : 0.f;
        }
        for (int idx = t; idx < 2048; idx += 256) {
            const int nn = idx & 63, kk = idx >> 6;
            const int k = k0 + kk, col = n0 + nn;
            sB[kk * 68 + nn] = (k < K && col < FH) ? Wblk[(size_t)k * FH + col] : 0.f;
        }
        __syncthreads();
        #pragma unroll 8
        for (int kk = 0; kk < 32; ++kk) {
            const float a0 = sA[(ty * 4 + 0) * 36 + kk];
            const float a1 = sA[(ty * 4 + 1) * 36 + kk];
            const float a2 = sA[(ty * 4 + 2) * 36 + kk];
            const float a3 = sA[(ty * 4 + 3) * 36 + kk];
            const float4 bb = *(const float4*)&sB[kk * 68 + tx * 4];
            acc[0][0] += a0 * bb.x; acc[0][1] += a0 * bb.y; acc[0][2] += a0 * bb.z; acc[0][3] += a0 * bb.w;
            acc[1][0] += a1 * bb.x; acc[1][1] += a1 * bb.y; acc[1][2] += a1 * bb.z; acc[1][3] += a1 * bb.w;
            acc[2][0] += a2 * bb.x; acc[2][1] += a2 * bb.y; acc[2][2] += a2 * bb.z; acc[2][3] += a2 * bb.w;
            acc[3][0] += a3 * bb.x; acc[3][1] += a3 * bb.y; acc[3][2] += a3 * bb.z; acc[3][3] += a3 * bb.w;
        }
        __syncthreads();
    }

    #pragma unroll
    for (int r = 0; r < 4; ++r) {
        const int row = m0 + ty * 4 + r;
        #pragma unroll
        for (int c = 0; c < 4; ++c) {
            const int col = n0 + tx * 4 + c;
            if (col < FH) {
                float v = fast_tanh(acc[r][c] + Bias[tp * FH + col]);
                if (RES) v += A[((size_t)tp * 1024 + row) * K + col];
                Out[((size_t)tp * 1024 + row) * FH + col] = v;
            }
        }
    }
}

// ---------------------------------------------------------------------------
// k_out: one wave per atom: out = h . W3 + b3
// ---------------------------------------------------------------------------
__global__ __launch_bounds__(256) void k_out(
    const float* __restrict__ Hin, const float* __restrict__ W3,
    const float* __restrict__ b3, float* __restrict__ out)
{
    const int wave = (int)((blockIdx.x * 256 + threadIdx.x) >> 6); // 0..2047
    const int lane = threadIdx.x & 63;
    const int tp = wave >> 10;
    const int rem = wave & 1023;
    const int b = rem >> 8, n = rem & 255;
    const float* h = Hin + (size_t)wave * FH;
    const float* wv = W3 + tp * FH;
    float s = 0.f;
    for (int k = lane; k < FH; k += 64) s += h[k] * wv[k];
    #pragma unroll
    for (int off = 32; off > 0; off >>= 1) s += __shfl_down(s, off);
    if (lane == 0) out[b * 512 + tp * 256 + n] = s + b3[tp];
}

// ---------------------------------------------------------------------------
extern "C" void kernel_launch(void* const* d_in, const int* in_sizes, int n_in,
                              void* d_out, int out_size, void* d_ws, size_t ws_size,
                              hipStream_t stream)
{
    const float* Ri  = (const float*)d_in[0];
    const float* eW0 = (const float*)d_in[1];
    const float* eB0 = (const float*)d_in[2];
    const float* eW1 = (const float*)d_in[3];
    const float* eB1 = (const float*)d_in[4];
    const float* eW2 = (const float*)d_in[5];
    const float* eB2 = (const float*)d_in[6];
    const float* fW0 = (const float*)d_in[7];
    const float* fb0 = (const float*)d_in[8];
    const float* fW1 = (const float*)d_in[9];
    const float* fb1 = (const float*)d_in[10];
    const float* fW2 = (const float*)d_in[11];
    const float* fb2 = (const float*)d_in[12];
    const float* fW3 = (const float*)d_in[13];
    const float* fb3 = (const float*)d_in[14];

    float* DR = (float*)d_ws;                      // 2*1024*1600 fp32
    float* hA = DR + (size_t)2 * 1024 * FIT_IN;    // 2*1024*240
    float* hB = hA + (size_t)2 * 1024 * FH;        // 2*1024*240

    k_emb<<<dim3(2048), dim3(256), 0, stream>>>(Ri, eW0, eB0, eW1, eB1, eW2, eB2, DR);
    k_fit<FIT_IN, false><<<dim3(4, 16, 2), dim3(256), 0, stream>>>(DR, fW0, fb0, hA);
    k_fit<FH, true><<<dim3(4, 16, 2), dim3(256), 0, stream>>>(hA, fW1, fb1, hB);
    k_fit<FH, true><<<dim3(4, 16, 2), dim3(256), 0, stream>>>(hB, fW2, fb2, hA);
    k_out<<<dim3(512), dim3(256), 0, stream>>>(hA, fW3, fb3, (float*)d_out);
}

// Round 3
// 500.733 us; speedup vs baseline: 1.9518x; 1.2601x over previous
//
#include <hip/hip_runtime.h>
#include <hip/hip_bf16.h>

#define FH 240
#define FIT_IN 1600

__device__ __forceinline__ float fast_tanh(float x) {
    float e2 = __builtin_amdgcn_exp2f(x * 2.8853900817779268f);
    return 1.0f - 2.0f * __builtin_amdgcn_rcpf(e2 + 1.0f);
}

// ---------------------------------------------------------------------------
// k_emb: one block per atom (b,i,n). 256 threads = 4 waves.  (unchanged R2)
// ---------------------------------------------------------------------------
#define OFF_R    0
#define OFF_W0   512
#define OFF_B0   540
#define OFF_B1   568
#define OFF_B2   620
#define OFF_W1   720
#define OFF_W2H  2020
#define OFF_H0T  4620
#define OFF_H1T  7920
#define OFF_XYZ  14520
#define SMEM_F   14920

__global__ __launch_bounds__(256) void k_emb(
    const float* __restrict__ Ri,
    const float* __restrict__ eW0, const float* __restrict__ eB0,
    const float* __restrict__ eW1, const float* __restrict__ eB1,
    const float* __restrict__ eW2, const float* __restrict__ eB2,
    float* __restrict__ DRws)
{
    __shared__ float sm[SMEM_F];

    const int t    = threadIdx.x;
    const int w    = t >> 6;
    const int lane = t & 63;
    const int mi   = lane >> 3;
    const int gi   = lane & 7;
    const int mrow = w * 32 + mi * 4;

    const int blk = blockIdx.x;
    const int b   = blk >> 9;
    const int i   = (blk >> 8) & 1;
    const int n   = blk & 255;

    for (int idx = t; idx < 400; idx += 256) sm[OFF_XYZ + idx] = 0.f;

    float partial[4][16];
    #pragma unroll
    for (int c = 0; c < 4; ++c)
        #pragma unroll
        for (int q = 0; q < 16; ++q) partial[c][q] = 0.f;

    const size_t riAtom = ((size_t)(b * 512 + i * 256 + n)) * 256;

    for (int j = 0; j < 2; ++j) {
        const int e = i * 2 + j;
        __syncthreads();

        for (int idx = t; idx < 1250; idx += 256) {
            int k = idx / 50, g = idx - k * 50;
            sm[OFF_W1 + k * 52 + g] = eW1[e * 1250 + idx];
        }
        if (t < 25)       { sm[OFF_W0 + t] = eW0[e * 25 + t]; sm[OFF_B0 + t] = eB0[e * 25 + t]; }
        else if (t < 75)  { sm[OFF_B1 + (t - 25)] = eB1[e * 50 + (t - 25)]; }
        else if (t < 175) { sm[OFF_B2 + (t - 75)] = eB2[e * 100 + (t - 75)]; }
        if (t < 128) {
            float4 r = *(const float4*)(Ri + (riAtom + (size_t)j * 128 + t) * 4);
            *(float4*)&sm[OFF_R + t * 4] = r;
        }
        __syncthreads();

        if (t < 128) {
            const float S = sm[OFF_R + t * 4];
            #pragma unroll
            for (int k = 0; k < 25; ++k) {
                sm[OFF_H0T + k * 132 + t] = fast_tanh(S * sm[OFF_W0 + k] + sm[OFF_B0 + k]);
            }
        }
        __syncthreads();

        {
            float acc[4][8];
            #pragma unroll
            for (int r = 0; r < 4; ++r)
                #pragma unroll
                for (int c = 0; c < 8; ++c) acc[r][c] = 0.f;

            #pragma unroll 5
            for (int k = 0; k < 25; ++k) {
                const float4 a  = *(const float4*)&sm[OFF_H0T + k * 132 + mrow];
                const float4 b0 = *(const float4*)&sm[OFF_W1 + k * 52 + gi * 8];
                const float4 b1 = *(const float4*)&sm[OFF_W1 + k * 52 + gi * 8 + 4];
                #define FMA_ROW(r, av) \
                    acc[r][0] += (av) * b0.x; acc[r][1] += (av) * b0.y; \
                    acc[r][2] += (av) * b0.z; acc[r][3] += (av) * b0.w; \
                    acc[r][4] += (av) * b1.x; acc[r][5] += (av) * b1.y; \
                    acc[r][6] += (av) * b1.z; acc[r][7] += (av) * b1.w;
                FMA_ROW(0, a.x) FMA_ROW(1, a.y) FMA_ROW(2, a.z) FMA_ROW(3, a.w)
            }
            #pragma unroll
            for (int c = 0; c < 8; ++c) {
                const int g = gi * 8 + c;
                if (g < 50) {
                    const int gm = (g < 25) ? g : g - 25;
                    const float4 h0r = *(const float4*)&sm[OFF_H0T + gm * 132 + mrow];
                    const float bias = sm[OFF_B1 + g];
                    float4 o;
                    o.x = fast_tanh(acc[0][c] + bias) + h0r.x;
                    o.y = fast_tanh(acc[1][c] + bias) + h0r.y;
                    o.z = fast_tanh(acc[2][c] + bias) + h0r.z;
                    o.w = fast_tanh(acc[3][c] + bias) + h0r.w;
                    *(float4*)&sm[OFF_H1T + g * 132 + mrow] = o;
                }
            }
        }

        for (int half = 0; half < 2; ++half) {
            __syncthreads();
            for (int idx = t; idx < 2500; idx += 256) {
                int k = idx / 50, g = idx - k * 50;
                sm[OFF_W2H + k * 52 + g] = eW2[e * 5000 + k * 100 + half * 50 + g];
            }
            __syncthreads();

            float acc[4][8];
            #pragma unroll
            for (int r = 0; r < 4; ++r)
                #pragma unroll
                for (int c = 0; c < 8; ++c) acc[r][c] = 0.f;

            #pragma unroll 5
            for (int k = 0; k < 50; ++k) {
                const float4 a  = *(const float4*)&sm[OFF_H1T + k * 132 + mrow];
                const float4 b0 = *(const float4*)&sm[OFF_W2H + k * 52 + gi * 8];
                const float4 b1 = *(const float4*)&sm[OFF_W2H + k * 52 + gi * 8 + 4];
                FMA_ROW(0, a.x) FMA_ROW(1, a.y) FMA_ROW(2, a.z) FMA_ROW(3, a.w)
            }

            const float4 Rv0 = *(const float4*)&sm[OFF_R + (mrow + 0) * 4];
            const float4 Rv1 = *(const float4*)&sm[OFF_R + (mrow + 1) * 4];
            const float4 Rv2 = *(const float4*)&sm[OFF_R + (mrow + 2) * 4];
            const float4 Rv3 = *(const float4*)&sm[OFF_R + (mrow + 3) * 4];
            #pragma unroll
            for (int c = 0; c < 8; ++c) {
                const int g  = gi * 8 + c;
                const int gq = (g < 50) ? g : 49;
                const float4 h1r = *(const float4*)&sm[OFF_H1T + gq * 132 + mrow];
                const float bias = sm[OFF_B2 + half * 50 + gq];
                const float g0 = fast_tanh(acc[0][c] + bias) + h1r.x;
                const float g1 = fast_tanh(acc[1][c] + bias) + h1r.y;
                const float g2 = fast_tanh(acc[2][c] + bias) + h1r.z;
                const float g3 = fast_tanh(acc[3][c] + bias) + h1r.w;
                const int q = half * 8 + c;
                partial[0][q] += Rv0.x * g0 + Rv1.x * g1 + Rv2.x * g2 + Rv3.x * g3;
                partial[1][q] += Rv0.y * g0 + Rv1.y * g1 + Rv2.y * g2 + Rv3.y * g3;
                partial[2][q] += Rv0.z * g0 + Rv1.z * g1 + Rv2.z * g2 + Rv3.z * g3;
                partial[3][q] += Rv0.w * g0 + Rv1.w * g1 + Rv2.w * g2 + Rv3.w * g3;
            }
        }
    }

    #pragma unroll
    for (int cc = 0; cc < 4; ++cc)
        #pragma unroll
        for (int q = 0; q < 16; ++q) {
            float v = partial[cc][q];
            v += __shfl_xor(v, 8, 64);
            v += __shfl_xor(v, 16, 64);
            v += __shfl_xor(v, 32, 64);
            partial[cc][q] = v;
        }
    if (mi == 0) {
        #pragma unroll
        for (int cc = 0; cc < 4; ++cc)
            #pragma unroll
            for (int q = 0; q < 16; ++q) {
                const int half = q >> 3, c = q & 7;
                const int g = gi * 8 + c;
                if (g < 50)
                    atomicAdd(&sm[OFF_XYZ + cc * 100 + half * 50 + g], partial[cc][q]);
            }
    }
    __syncthreads();

    const float inv = 1.0f / 65536.0f;
    float* dr = DRws + (((size_t)i * 4 + b) * 256 + n) * FIT_IN;
    for (int idx = t; idx < FIT_IN; idx += 256) {
        const int g = idx >> 4, h = idx & 15;
        const float v = sm[OFF_XYZ + g] * sm[OFF_XYZ + h]
                      + sm[OFF_XYZ + 100 + g] * sm[OFF_XYZ + 100 + h]
                      + sm[OFF_XYZ + 200 + g] * sm[OFF_XYZ + 200 + h]
                      + sm[OFF_XYZ + 300 + g] * sm[OFF_XYZ + 300 + h];
        dr[idx] = v * inv;
    }
}

// ---------------------------------------------------------------------------
// k_fit_part: partial GEMM over one K-slice.
// A:[2][1024][K]  W:[2][K][240]  P:[KSPLIT*2][1024][240]
// grid (4 n-tiles, 16 m-tiles, 2*KSPLIT), 256 threads; 64x64 tile, 4x4/lane.
// sA stored transposed [kk][m] (stride 68 => b128-aligned) so both operands
// are ds_read_b128: 2 b128 per 16 FMA.
// ---------------------------------------------------------------------------
template<int K, int KSPLIT>
__global__ __launch_bounds__(256) void k_fit_part(
    const float* __restrict__ A, const float* __restrict__ W,
    float* __restrict__ P)
{
    constexpr int CHUNK = K / KSPLIT;
    __shared__ float sA[32 * 68];
    __shared__ float sB[32 * 68];

    const int t  = threadIdx.x;
    const int tx = t & 15, ty = t >> 4;
    const int n0 = blockIdx.x * 64;
    const int m0 = blockIdx.y * 64;
    const int tp = blockIdx.z & 1;
    const int ks = blockIdx.z >> 1;
    const int kbeg = ks * CHUNK, kend = kbeg + CHUNK;

    const float* Ablk = A + ((size_t)tp * 1024 + m0) * K;
    const float* Wblk = W + (size_t)tp * K * FH;

    float acc[4][4];
    #pragma unroll
    for (int r = 0; r < 4; ++r)
        #pragma unroll
        for (int c = 0; c < 4; ++c) acc[r][c] = 0.f;

    for (int k0 = kbeg; k0 < kend; k0 += 32) {
        for (int idx = t; idx < 2048; idx += 256) {
            const int kk = idx & 31, m = idx >> 5;
            const int k = k0 + kk;
            sA[kk * 68 + m] = (k < kend) ? Ablk[(size_t)m * K + k] : 0.f;
        }
        for (int idx = t; idx < 2048; idx += 256) {
            const int nn = idx & 63, kk = idx >> 6;
            const int k = k0 + kk, col = n0 + nn;
            sB[kk * 68 + nn] = (k < kend && col < FH) ? Wblk[(size_t)k * FH + col] : 0.f;
        }
        __syncthreads();
        #pragma unroll
        for (int kk = 0; kk < 32; ++kk) {
            const float4 a  = *(const float4*)&sA[kk * 68 + ty * 4];
            const float4 bb = *(const float4*)&sB[kk * 68 + tx * 4];
            acc[0][0] += a.x * bb.x; acc[0][1] += a.x * bb.y; acc[0][2] += a.x * bb.z; acc[0][3] += a.x * bb.w;
            acc[1][0] += a.y * bb.x; acc[1][1] += a.y * bb.y; acc[1][2] += a.y * bb.z; acc[1][3] += a.y * bb.w;
            acc[2][0] += a.z * bb.x; acc[2][1] += a.z * bb.y; acc[2][2] += a.z * bb.z; acc[2][3] += a.z * bb.w;
            acc[3][0] += a.w * bb.x; acc[3][1] += a.w * bb.y; acc[3][2] += a.w * bb.z; acc[3][3] += a.w * bb.w;
        }
        __syncthreads();
    }

    float* Pblk = P + ((size_t)(ks * 2 + tp) * 1024 + m0) * FH;
    #pragma unroll
    for (int r = 0; r < 4; ++r) {
        const int row = ty * 4 + r;
        #pragma unroll
        for (int c = 0; c < 4; ++c) {
            const int col = n0 + tx * 4 + c;
            if (col < FH) Pblk[(size_t)row * FH + col] = acc[r][c];
        }
    }
}

// ---------------------------------------------------------------------------
// k_fit_reduce: Out = tanh(sum_ks P + bias) [+ Ain if RES]
// ---------------------------------------------------------------------------
template<int KSPLIT, bool RES>
__global__ __launch_bounds__(256) void k_fit_reduce(
    const float* __restrict__ P, const float* __restrict__ Bias,
    const float* __restrict__ Ain, float* __restrict__ Out)
{
    const int idx = blockIdx.x * 256 + threadIdx.x;
    if (idx >= 2 * 1024 * FH) return;
    const int tp  = idx / (1024 * FH);
    const int rem = idx - tp * (1024 * FH);
    const int col = rem % FH;
    float s = 0.f;
    #pragma unroll
    for (int ks = 0; ks < KSPLIT; ++ks)
        s += P[(size_t)(ks * 2 + tp) * 1024 * FH + rem];
    float v = fast_tanh(s + Bias[tp * FH + col]);
    if (RES) v += Ain[idx];
    Out[idx] = v;
}

// ---------------------------------------------------------------------------
// k_out: one wave per atom: out = h . W3 + b3
// ---------------------------------------------------------------------------
__global__ __launch_bounds__(256) void k_out(
    const float* __restrict__ Hin, const float* __restrict__ W3,
    const float* __restrict__ b3, float* __restrict__ out)
{
    const int wave = (int)((blockIdx.x * 256 + threadIdx.x) >> 6);
    const int lane = threadIdx.x & 63;
    const int tp = wave >> 10;
    const int rem = wave & 1023;
    const int b = rem >> 8, n = rem & 255;
    const float* h = Hin + (size_t)wave * FH;
    const float* wv = W3 + tp * FH;
    float s = 0.f;
    for (int k = lane; k < FH; k += 64) s += h[k] * wv[k];
    #pragma unroll
    for (int off = 32; off > 0; off >>= 1) s += __shfl_down(s, off);
    if (lane == 0) out[b * 512 + tp * 256 + n] = s + b3[tp];
}

// ---------------------------------------------------------------------------
extern "C" void kernel_launch(void* const* d_in, const int* in_sizes, int n_in,
                              void* d_out, int out_size, void* d_ws, size_t ws_size,
                              hipStream_t stream)
{
    const float* Ri  = (const float*)d_in[0];
    const float* eW0 = (const float*)d_in[1];
    const float* eB0 = (const float*)d_in[2];
    const float* eW1 = (const float*)d_in[3];
    const float* eB1 = (const float*)d_in[4];
    const float* eW2 = (const float*)d_in[5];
    const float* eB2 = (const float*)d_in[6];
    const float* fW0 = (const float*)d_in[7];
    const float* fb0 = (const float*)d_in[8];
    const float* fW1 = (const float*)d_in[9];
    const float* fb1 = (const float*)d_in[10];
    const float* fW2 = (const float*)d_in[11];
    const float* fb2 = (const float*)d_in[12];
    const float* fW3 = (const float*)d_in[13];
    const float* fb3 = (const float*)d_in[14];

    float* DR = (float*)d_ws;                         // 2*1024*1600
    float* P  = DR + (size_t)2 * 1024 * FIT_IN;       // 8*1024*240 (KSPLIT=4 x 2 types)
    float* hA = P  + (size_t)8 * 1024 * FH;           // 2*1024*240
    float* hB = hA + (size_t)2 * 1024 * FH;           // 2*1024*240

    const int NOUT = 2 * 1024 * FH;
    const int RBLK = (NOUT + 255) / 256;

    k_emb<<<dim3(2048), dim3(256), 0, stream>>>(Ri, eW0, eB0, eW1, eB1, eW2, eB2, DR);

    k_fit_part<FIT_IN, 4><<<dim3(4, 16, 8), dim3(256), 0, stream>>>(DR, fW0, P);
    k_fit_reduce<4, false><<<dim3(RBLK), dim3(256), 0, stream>>>(P, fb0, nullptr, hA);

    k_fit_part<FH, 4><<<dim3(4, 16, 8), dim3(256), 0, stream>>>(hA, fW1, P);
    k_fit_reduce<4, true><<<dim3(RBLK), dim3(256), 0, stream>>>(P, fb1, hA, hB);

    k_fit_part<FH, 4><<<dim3(4, 16, 8), dim3(256), 0, stream>>>(hB, fW2, P);
    k_fit_reduce<4, true><<<dim3(RBLK), dim3(256), 0, stream>>>(P, fb2, hB, hA);

    k_out<<<dim3(512), dim3(256), 0, stream>>>(hA, fW3, fb3, (float*)d_out);
}

// Round 4
// 494.834 us; speedup vs baseline: 1.9751x; 1.0119x over previous
//
#include <hip/hip_runtime.h>
#include <hip/hip_bf16.h>

#define FH 240
#define FIT_IN 1600

__device__ __forceinline__ float fast_tanh(float x) {
    float e2 = __builtin_amdgcn_exp2f(x * 2.8853900817779268f);
    return 1.0f - 2.0f * __builtin_amdgcn_rcpf(e2 + 1.0f);
}

// ---------------------------------------------------------------------------
// k_emb: one block per 4 atoms of one type. 256 threads = 4 waves.
// Weights (W1 + full W2) staged once per j-phase, amortized over 4 atoms.
// Lane map mi=lane&7, gi=lane>>3 so b128 phases span mi (all 32 banks).
// ---------------------------------------------------------------------------
#define EOFF_W0   0       // 25 (pad 28)
#define EOFF_B0   28      // 25 (pad 28)
#define EOFF_B1   56      // 50 (pad 52)
#define EOFF_B2   108     // 100
#define EOFF_W1   208     // 25 x 52
#define EOFF_W2   1508    // 50 x 104 (two 52-aligned halves per k)
#define EOFF_H0T  6708    // 25 x 132  [k][m]
#define EOFF_H1T  10008   // 50 x 132  [k][m]
#define EOFF_RT   16608   // 4 x 132   [c][m]
#define EOFF_XYZ  17136   // 4 atoms x 400
#define ESMEM     18736   // 74944 B -> 2 blocks/CU

__global__ __launch_bounds__(256) void k_emb(
    const float* __restrict__ Ri,
    const float* __restrict__ eW0, const float* __restrict__ eB0,
    const float* __restrict__ eW1, const float* __restrict__ eB1,
    const float* __restrict__ eW2, const float* __restrict__ eB2,
    float* __restrict__ DRws)
{
    __shared__ float sm[ESMEM];

    const int t    = threadIdx.x;
    const int w    = t >> 6;
    const int lane = t & 63;
    const int mi   = lane & 7;        // m-lane axis (low bits: phases span banks)
    const int gi   = lane >> 3;       // g-lane axis
    const int mrow = w * 32 + mi * 4;

    const int blk = blockIdx.x;       // 0..511
    const int b   = blk >> 7;
    const int i   = (blk >> 6) & 1;
    const int n0  = (blk & 63) * 4;

    for (int idx = t; idx < 1600; idx += 256) sm[EOFF_XYZ + idx] = 0.f;

    for (int j = 0; j < 2; ++j) {
        const int e = i * 2 + j;
        __syncthreads();   // prior-phase readers done (also covers XYZ init)

        // ---- stage weights for this (i,j) once, reused by 4 atoms ----
        for (int idx = t; idx < 1250; idx += 256) {
            int k = idx / 50, g = idx - k * 50;
            sm[EOFF_W1 + k * 52 + g] = eW1[e * 1250 + idx];
        }
        for (int idx = t; idx < 5000; idx += 256) {
            int k = idx / 100, r = idx - k * 100;
            int half = r / 50, g = r - half * 50;
            sm[EOFF_W2 + k * 104 + half * 52 + g] = eW2[e * 5000 + idx];
        }
        if (t < 25)       { sm[EOFF_W0 + t] = eW0[e * 25 + t]; sm[EOFF_B0 + t] = eB0[e * 25 + t]; }
        else if (t < 75)  { sm[EOFF_B1 + (t - 25)] = eB1[e * 50 + (t - 25)]; }
        else if (t < 175) { sm[EOFF_B2 + (t - 75)] = eB2[e * 100 + (t - 75)]; }

        for (int a = 0; a < 4; ++a) {
            __syncthreads();  // weights staged / prior atom's RT,H1T reads done

            // ---- stage R transposed for atom a ----
            if (t < 128) {
                const size_t riAtom = ((size_t)(b * 512 + i * 256 + n0 + a)) * 256;
                float4 r = *(const float4*)(Ri + (riAtom + (size_t)j * 128 + t) * 4);
                sm[EOFF_RT + 0 * 132 + t] = r.x;
                sm[EOFF_RT + 1 * 132 + t] = r.y;
                sm[EOFF_RT + 2 * 132 + t] = r.z;
                sm[EOFF_RT + 3 * 132 + t] = r.w;
            }
            __syncthreads();

            // ---- layer 1: h0 transposed [k][m] ----
            if (t < 128) {
                const float S = sm[EOFF_RT + t];
                #pragma unroll
                for (int k = 0; k < 25; ++k)
                    sm[EOFF_H0T + k * 132 + t] = fast_tanh(S * sm[EOFF_W0 + k] + sm[EOFF_B0 + k]);
            }
            __syncthreads();

            // ---- GEMM1: M=128 N=50 K=25, 4x8 per lane ----
            {
                float acc[4][8];
                #pragma unroll
                for (int r = 0; r < 4; ++r)
                    #pragma unroll
                    for (int c = 0; c < 8; ++c) acc[r][c] = 0.f;

                #pragma unroll 5
                for (int k = 0; k < 25; ++k) {
                    const float4 av = *(const float4*)&sm[EOFF_H0T + k * 132 + mrow];
                    const float4 b0 = *(const float4*)&sm[EOFF_W1 + k * 52 + gi * 8];
                    const float4 b1 = *(const float4*)&sm[EOFF_W1 + k * 52 + gi * 8 + 4];
                    #define FMA_ROW(r, s) \
                        acc[r][0] += (s) * b0.x; acc[r][1] += (s) * b0.y; \
                        acc[r][2] += (s) * b0.z; acc[r][3] += (s) * b0.w; \
                        acc[r][4] += (s) * b1.x; acc[r][5] += (s) * b1.y; \
                        acc[r][6] += (s) * b1.z; acc[r][7] += (s) * b1.w;
                    FMA_ROW(0, av.x) FMA_ROW(1, av.y) FMA_ROW(2, av.z) FMA_ROW(3, av.w)
                }
                #pragma unroll
                for (int c = 0; c < 8; ++c) {
                    const int g = gi * 8 + c;
                    if (g < 50) {
                        const int gm = (g < 25) ? g : g - 25;
                        const float4 h0r = *(const float4*)&sm[EOFF_H0T + gm * 132 + mrow];
                        const float bias = sm[EOFF_B1 + g];
                        float4 o;
                        o.x = fast_tanh(acc[0][c] + bias) + h0r.x;
                        o.y = fast_tanh(acc[1][c] + bias) + h0r.y;
                        o.z = fast_tanh(acc[2][c] + bias) + h0r.z;
                        o.w = fast_tanh(acc[3][c] + bias) + h0r.w;
                        *(float4*)&sm[EOFF_H1T + g * 132 + mrow] = o;
                    }
                }
            }
            __syncthreads();

            // ---- GEMM2 halves + fused neighbor reduction ----
            float partial[4][16];
            #pragma unroll
            for (int c = 0; c < 4; ++c)
                #pragma unroll
                for (int q = 0; q < 16; ++q) partial[c][q] = 0.f;

            const float4 rt0 = *(const float4*)&sm[EOFF_RT + 0 * 132 + mrow];
            const float4 rt1 = *(const float4*)&sm[EOFF_RT + 1 * 132 + mrow];
            const float4 rt2 = *(const float4*)&sm[EOFF_RT + 2 * 132 + mrow];
            const float4 rt3 = *(const float4*)&sm[EOFF_RT + 3 * 132 + mrow];

            for (int half = 0; half < 2; ++half) {
                float acc[4][8];
                #pragma unroll
                for (int r = 0; r < 4; ++r)
                    #pragma unroll
                    for (int c = 0; c < 8; ++c) acc[r][c] = 0.f;

                #pragma unroll 5
                for (int k = 0; k < 50; ++k) {
                    const float4 av = *(const float4*)&sm[EOFF_H1T + k * 132 + mrow];
                    const float4 b0 = *(const float4*)&sm[EOFF_W2 + k * 104 + half * 52 + gi * 8];
                    const float4 b1 = *(const float4*)&sm[EOFF_W2 + k * 104 + half * 52 + gi * 8 + 4];
                    FMA_ROW(0, av.x) FMA_ROW(1, av.y) FMA_ROW(2, av.z) FMA_ROW(3, av.w)
                }
                #pragma unroll
                for (int c = 0; c < 8; ++c) {
                    const int g = gi * 8 + c;
                    if (g < 50) {
                        const float4 h1r = *(const float4*)&sm[EOFF_H1T + g * 132 + mrow];
                        const float bias = sm[EOFF_B2 + half * 50 + g];
                        const float g0 = fast_tanh(acc[0][c] + bias) + h1r.x;
                        const float g1 = fast_tanh(acc[1][c] + bias) + h1r.y;
                        const float g2 = fast_tanh(acc[2][c] + bias) + h1r.z;
                        const float g3 = fast_tanh(acc[3][c] + bias) + h1r.w;
                        const int q = half * 8 + c;
                        partial[0][q] += rt0.x * g0 + rt0.y * g1 + rt0.z * g2 + rt0.w * g3;
                        partial[1][q] += rt1.x * g0 + rt1.y * g1 + rt1.z * g2 + rt1.w * g3;
                        partial[2][q] += rt2.x * g0 + rt2.y * g1 + rt2.z * g2 + rt2.w * g3;
                        partial[3][q] += rt3.x * g0 + rt3.y * g1 + rt3.z * g2 + rt3.w * g3;
                    }
                }
            }

            // reduce over mi (lane bits 0..2), then one atomicAdd per (w,gi)
            #pragma unroll
            for (int cc = 0; cc < 4; ++cc)
                #pragma unroll
                for (int q = 0; q < 16; ++q) {
                    float v = partial[cc][q];
                    v += __shfl_xor(v, 1, 64);
                    v += __shfl_xor(v, 2, 64);
                    v += __shfl_xor(v, 4, 64);
                    partial[cc][q] = v;
                }
            if (mi == 0) {
                #pragma unroll
                for (int cc = 0; cc < 4; ++cc)
                    #pragma unroll
                    for (int q = 0; q < 16; ++q) {
                        const int half = q >> 3, c = q & 7;
                        const int g = gi * 8 + c;
                        if (g < 50)
                            atomicAdd(&sm[EOFF_XYZ + a * 400 + cc * 100 + half * 50 + g],
                                      partial[cc][q]);
                    }
            }
        }
    }
    __syncthreads();

    // ---- DR epilogue for the 4 atoms ----
    const float inv = 1.0f / 65536.0f;
    for (int a = 0; a < 4; ++a) {
        const float* xz = &sm[EOFF_XYZ + a * 400];
        float* dr = DRws + (((size_t)i * 4 + b) * 256 + (n0 + a)) * FIT_IN;
        for (int idx = t; idx < FIT_IN; idx += 256) {
            const int g = idx >> 4, h = idx & 15;
            dr[idx] = (xz[g] * xz[h] + xz[100 + g] * xz[100 + h]
                     + xz[200 + g] * xz[200 + h] + xz[300 + g] * xz[300 + h]) * inv;
        }
    }
}

// ---------------------------------------------------------------------------
// k_fit_part: partial GEMM over one K-slice (unchanged from R3).
// ---------------------------------------------------------------------------
template<int K, int KSPLIT>
__global__ __launch_bounds__(256) void k_fit_part(
    const float* __restrict__ A, const float* __restrict__ W,
    float* __restrict__ P)
{
    constexpr int CHUNK = K / KSPLIT;
    __shared__ float sA[32 * 68];
    __shared__ float sB[32 * 68];

    const int t  = threadIdx.x;
    const int tx = t & 15, ty = t >> 4;
    const int n0 = blockIdx.x * 64;
    const int m0 = blockIdx.y * 64;
    const int tp = blockIdx.z & 1;
    const int ks = blockIdx.z >> 1;
    const int kbeg = ks * CHUNK, kend = kbeg + CHUNK;

    const float* Ablk = A + ((size_t)tp * 1024 + m0) * K;
    const float* Wblk = W + (size_t)tp * K * FH;

    float acc[4][4];
    #pragma unroll
    for (int r = 0; r < 4; ++r)
        #pragma unroll
        for (int c = 0; c < 4; ++c) acc[r][c] = 0.f;

    for (int k0 = kbeg; k0 < kend; k0 += 32) {
        for (int idx = t; idx < 2048; idx += 256) {
            const int kk = idx & 31, m = idx >> 5;
            const int k = k0 + kk;
            sA[kk * 68 + m] = (k < kend) ? Ablk[(size_t)m * K + k] : 0.f;
        }
        for (int idx = t; idx < 2048; idx += 256) {
            const int nn = idx & 63, kk = idx >> 6;
            const int k = k0 + kk, col = n0 + nn;
            sB[kk * 68 + nn] = (k < kend && col < FH) ? Wblk[(size_t)k * FH + col] : 0.f;
        }
        __syncthreads();
        #pragma unroll
        for (int kk = 0; kk < 32; ++kk) {
            const float4 a  = *(const float4*)&sA[kk * 68 + ty * 4];
            const float4 bb = *(const float4*)&sB[kk * 68 + tx * 4];
            acc[0][0] += a.x * bb.x; acc[0][1] += a.x * bb.y; acc[0][2] += a.x * bb.z; acc[0][3] += a.x * bb.w;
            acc[1][0] += a.y * bb.x; acc[1][1] += a.y * bb.y; acc[1][2] += a.y * bb.z; acc[1][3] += a.y * bb.w;
            acc[2][0] += a.z * bb.x; acc[2][1] += a.z * bb.y; acc[2][2] += a.z * bb.z; acc[2][3] += a.z * bb.w;
            acc[3][0] += a.w * bb.x; acc[3][1] += a.w * bb.y; acc[3][2] += a.w * bb.z; acc[3][3] += a.w * bb.w;
        }
        __syncthreads();
    }

    float* Pblk = P + ((size_t)(ks * 2 + tp) * 1024 + m0) * FH;
    #pragma unroll
    for (int r = 0; r < 4; ++r) {
        const int row = ty * 4 + r;
        #pragma unroll
        for (int c = 0; c < 4; ++c) {
            const int col = n0 + tx * 4 + c;
            if (col < FH) Pblk[(size_t)row * FH + col] = acc[r][c];
        }
    }
}

// ---------------------------------------------------------------------------
// k_fit_reduce: Out = tanh(sum_ks P + bias) [+ Ain if RES]
// ---------------------------------------------------------------------------
template<int KSPLIT, bool RES>
__global__ __launch_bounds__(256) void k_fit_reduce(
    const float* __restrict__ P, const float* __restrict__ Bias,
    const float* __restrict__ Ain, float* __restrict__ Out)
{
    const int idx = blockIdx.x * 256 + threadIdx.x;
    if (idx >= 2 * 1024 * FH) return;
    const int tp  = idx / (1024 * FH);
    const int rem = idx - tp * (1024 * FH);
    const int col = rem % FH;
    float s = 0.f;
    #pragma unroll
    for (int ks = 0; ks < KSPLIT; ++ks)
        s += P[(size_t)(ks * 2 + tp) * 1024 * FH + rem];
    float v = fast_tanh(s + Bias[tp * FH + col]);
    if (RES) v += Ain[idx];
    Out[idx] = v;
}

// ---------------------------------------------------------------------------
// k_out: one wave per atom: out = h . W3 + b3
// ---------------------------------------------------------------------------
__global__ __launch_bounds__(256) void k_out(
    const float* __restrict__ Hin, const float* __restrict__ W3,
    const float* __restrict__ b3, float* __restrict__ out)
{
    const int wave = (int)((blockIdx.x * 256 + threadIdx.x) >> 6);
    const int lane = threadIdx.x & 63;
    const int tp = wave >> 10;
    const int rem = wave & 1023;
    const int b = rem >> 8, n = rem & 255;
    const float* h = Hin + (size_t)wave * FH;
    const float* wv = W3 + tp * FH;
    float s = 0.f;
    for (int k = lane; k < FH; k += 64) s += h[k] * wv[k];
    #pragma unroll
    for (int off = 32; off > 0; off >>= 1) s += __shfl_down(s, off);
    if (lane == 0) out[b * 512 + tp * 256 + n] = s + b3[tp];
}

// ---------------------------------------------------------------------------
extern "C" void kernel_launch(void* const* d_in, const int* in_sizes, int n_in,
                              void* d_out, int out_size, void* d_ws, size_t ws_size,
                              hipStream_t stream)
{
    const float* Ri  = (const float*)d_in[0];
    const float* eW0 = (const float*)d_in[1];
    const float* eB0 = (const float*)d_in[2];
    const float* eW1 = (const float*)d_in[3];
    const float* eB1 = (const float*)d_in[4];
    const float* eW2 = (const float*)d_in[5];
    const float* eB2 = (const float*)d_in[6];
    const float* fW0 = (const float*)d_in[7];
    const float* fb0 = (const float*)d_in[8];
    const float* fW1 = (const float*)d_in[9];
    const float* fb1 = (const float*)d_in[10];
    const float* fW2 = (const float*)d_in[11];
    const float* fb2 = (const float*)d_in[12];
    const float* fW3 = (const float*)d_in[13];
    const float* fb3 = (const float*)d_in[14];

    float* DR = (float*)d_ws;                         // 2*1024*1600
    float* P  = DR + (size_t)2 * 1024 * FIT_IN;       // 8*1024*240
    float* hA = P  + (size_t)8 * 1024 * FH;           // 2*1024*240
    float* hB = hA + (size_t)2 * 1024 * FH;           // 2*1024*240

    const int NOUT = 2 * 1024 * FH;
    const int RBLK = (NOUT + 255) / 256;

    k_emb<<<dim3(512), dim3(256), 0, stream>>>(Ri, eW0, eB0, eW1, eB1, eW2, eB2, DR);

    k_fit_part<FIT_IN, 4><<<dim3(4, 16, 8), dim3(256), 0, stream>>>(DR, fW0, P);
    k_fit_reduce<4, false><<<dim3(RBLK), dim3(256), 0, stream>>>(P, fb0, nullptr, hA);

    k_fit_part<FH, 4><<<dim3(4, 16, 8), dim3(256), 0, stream>>>(hA, fW1, P);
    k_fit_reduce<4, true><<<dim3(RBLK), dim3(256), 0, stream>>>(P, fb1, hA, hB);

    k_fit_part<FH, 4><<<dim3(4, 16, 8), dim3(256), 0, stream>>>(hB, fW2, P);
    k_fit_reduce<4, true><<<dim3(RBLK), dim3(256), 0, stream>>>(P, fb2, hB, hA);

    k_out<<<dim3(512), dim3(256), 0, stream>>>(hA, fW3, fb3, (float*)d_out);
}

// Round 5
// 461.959 us; speedup vs baseline: 2.1156x; 1.0712x over previous
//
#include <hip/hip_runtime.h>
#include <hip/hip_bf16.h>

#define FH 240
#define FIT_IN 1600
#define NK 2048            // table knots per e
#define TLO -16.0f
#define TINVH 64.0f        // knots per unit S (h = 1/64)

__device__ __forceinline__ float fast_tanh(float x) {
    float e2 = __builtin_amdgcn_exp2f(x * 2.8853900817779268f);
    return 1.0f - 2.0f * __builtin_amdgcn_rcpf(e2 + 1.0f);
}

// ---------------------------------------------------------------------------
// k_table: build piecewise-linear table T[e][knot][100] of the embedding MLP.
// Exact fp32 math (same ops as the former k_emb chain). 128 knots per block.
// ---------------------------------------------------------------------------
__global__ __launch_bounds__(128) void k_table(
    const float* __restrict__ eW0, const float* __restrict__ eB0,
    const float* __restrict__ eW1, const float* __restrict__ eB1,
    const float* __restrict__ eW2, const float* __restrict__ eB2,
    float* __restrict__ T)
{
    __shared__ float sT[128 * 100];
    const int e  = blockIdx.y;
    const int k0 = blockIdx.x * 128;
    const int t  = threadIdx.x;

    const float S = TLO + (float)(k0 + t) * (1.0f / TINVH);

    float h0[25];
    #pragma unroll
    for (int k = 0; k < 25; ++k)
        h0[k] = fast_tanh(S * eW0[e * 25 + k] + eB0[e * 25 + k]);

    float h1[50];
    #pragma unroll 2
    for (int g = 0; g < 50; ++g) {
        float acc = eB1[e * 50 + g];
        #pragma unroll 5
        for (int k = 0; k < 25; ++k) acc += h0[k] * eW1[e * 1250 + k * 50 + g];
        h1[g] = fast_tanh(acc) + h0[(g < 25) ? g : g - 25];
    }

    #pragma unroll 1
    for (int g = 0; g < 100; ++g) {
        float acc = eB2[e * 100 + g];
        #pragma unroll 5
        for (int k = 0; k < 50; ++k) acc += h1[k] * eW2[e * 5000 + k * 100 + g];
        sT[t * 100 + g] = fast_tanh(acc) + h1[(g < 50) ? g : g - 50];
    }
    __syncthreads();

    float* out = T + ((size_t)e * NK + k0) * 100;
    for (int idx = t; idx < 12800; idx += 128) out[idx] = sT[idx];
}

// ---------------------------------------------------------------------------
// k_xyz: per atom: gather+lerp G from table, reduce xyz[c][g], emit DR.
// One block per atom; waves 0-1 handle j=0, waves 2-3 handle j=1.
// ---------------------------------------------------------------------------
__global__ __launch_bounds__(256) void k_xyz(
    const float* __restrict__ Ri, const float* __restrict__ T,
    float* __restrict__ DRws)
{
    __shared__ float4 sR[256];
    __shared__ float  sF[256];
    __shared__ int    sI[256];
    __shared__ float  sXYZ[400];

    const int t   = threadIdx.x;
    const int blk = blockIdx.x;          // 0..2047
    const int b   = blk >> 9;
    const int i   = (blk >> 8) & 1;
    const int n   = blk & 255;

    for (int idx = t; idx < 400; idx += 256) sXYZ[idx] = 0.f;

    // stage R + bin index/frac for both j at once (thread = (j, m))
    {
        const int jj = t >> 7, m = t & 127;
        const size_t row = ((size_t)(b * 512 + i * 256 + n)) * 256 + jj * 128 + m;
        const float4 r = *(const float4*)(Ri + row * 4);
        sR[t] = r;
        float u = (r.x - TLO) * TINVH;
        int ii = (int)u;
        ii = (ii < 0) ? 0 : ((ii > NK - 2) ? NK - 2 : ii);
        sI[t] = ii;
        sF[t] = u - (float)ii;           // may be <0 or >1 -> linear extrapolation
    }
    __syncthreads();

    const int jj = t >> 7;               // wave-aligned j split
    const int g  = t & 127;
    if (g < 100) {
        const float* Te = T + ((size_t)(i * 2 + jj)) * NK * 100 + g;
        float a0 = 0.f, a1 = 0.f, a2 = 0.f, a3 = 0.f;
        #pragma unroll 4
        for (int m = 0; m < 128; ++m) {
            const int s = jj * 128 + m;
            const float4 R = sR[s];
            const float  f = sF[s];
            const float* p = Te + (size_t)sI[s] * 100;
            const float v0 = p[0], v1 = p[100];
            const float G = v0 + f * (v1 - v0);
            a0 += R.x * G; a1 += R.y * G; a2 += R.z * G; a3 += R.w * G;
        }
        atomicAdd(&sXYZ[g],       a0);
        atomicAdd(&sXYZ[100 + g], a1);
        atomicAdd(&sXYZ[200 + g], a2);
        atomicAdd(&sXYZ[300 + g], a3);
    }
    __syncthreads();

    const float inv = 1.0f / 65536.0f;
    float* dr = DRws + (((size_t)i * 4 + b) * 256 + n) * FIT_IN;
    for (int idx = t; idx < FIT_IN; idx += 256) {
        const int gg = idx >> 4, h = idx & 15;
        dr[idx] = (sXYZ[gg] * sXYZ[h] + sXYZ[100 + gg] * sXYZ[100 + h]
                 + sXYZ[200 + gg] * sXYZ[200 + h] + sXYZ[300 + gg] * sXYZ[300 + h]) * inv;
    }
}

// ---------------------------------------------------------------------------
// k_fit_part: partial GEMM over one K-slice. 128x128 tile, 8x8 per lane,
// K-chunk 16. A:[2][1024][K] W:[2][K][240] P:[KSPLIT*2][1024][240]
// grid (2 n-tiles, 8 m-tiles, 2*KSPLIT).
// ---------------------------------------------------------------------------
template<int K, int KSPLIT>
__global__ __launch_bounds__(256) void k_fit_part(
    const float* __restrict__ A, const float* __restrict__ W,
    float* __restrict__ P)
{
    constexpr int CHUNK = (K + KSPLIT - 1) / KSPLIT;
    __shared__ __attribute__((aligned(16))) float sA[16 * 132];
    __shared__ __attribute__((aligned(16))) float sB[16 * 132];

    const int t  = threadIdx.x;
    const int tx = t & 15, ty = t >> 4;
    const int n0 = blockIdx.x * 128;
    const int m0 = blockIdx.y * 128;
    const int tp = blockIdx.z & 1;
    const int ks = blockIdx.z >> 1;
    const int kbeg = ks * CHUNK;
    const int kend = (kbeg + CHUNK < K) ? (kbeg + CHUNK) : K;

    const float* Ablk = A + ((size_t)tp * 1024 + m0) * K;
    const float* Wblk = W + (size_t)tp * K * FH;

    float acc[2][2][4][4];
    #pragma unroll
    for (int rb = 0; rb < 2; ++rb)
        #pragma unroll
        for (int cb = 0; cb < 2; ++cb)
            #pragma unroll
            for (int r = 0; r < 4; ++r)
                #pragma unroll
                for (int c = 0; c < 4; ++c) acc[rb][cb][r][c] = 0.f;

    for (int k0 = kbeg; k0 < kend; k0 += 16) {
        for (int idx = t; idx < 2048; idx += 256) {
            const int m = idx >> 4, kk = idx & 15;
            const int k = k0 + kk;
            sA[kk * 132 + m] = (k < kend) ? Ablk[(size_t)m * K + k] : 0.f;
        }
        for (int idx = t; idx < 2048; idx += 256) {
            const int nn = idx & 127, kk = idx >> 7;
            const int k = k0 + kk, col = n0 + nn;
            sB[kk * 132 + nn] = (k < kend && col < FH) ? Wblk[(size_t)k * FH + col] : 0.f;
        }
        __syncthreads();
        #pragma unroll
        for (int kk = 0; kk < 16; ++kk) {
            const float4 a0 = *(const float4*)&sA[kk * 132 + ty * 4];
            const float4 a1 = *(const float4*)&sA[kk * 132 + ty * 4 + 64];
            const float4 b0 = *(const float4*)&sB[kk * 132 + tx * 4];
            const float4 b1 = *(const float4*)&sB[kk * 132 + tx * 4 + 64];
            #define ACC_TILE(rb, cb, av, bv) \
                acc[rb][cb][0][0] += (av).x * (bv).x; acc[rb][cb][0][1] += (av).x * (bv).y; \
                acc[rb][cb][0][2] += (av).x * (bv).z; acc[rb][cb][0][3] += (av).x * (bv).w; \
                acc[rb][cb][1][0] += (av).y * (bv).x; acc[rb][cb][1][1] += (av).y * (bv).y; \
                acc[rb][cb][1][2] += (av).y * (bv).z; acc[rb][cb][1][3] += (av).y * (bv).w; \
                acc[rb][cb][2][0] += (av).z * (bv).x; acc[rb][cb][2][1] += (av).z * (bv).y; \
                acc[rb][cb][2][2] += (av).z * (bv).z; acc[rb][cb][2][3] += (av).z * (bv).w; \
                acc[rb][cb][3][0] += (av).w * (bv).x; acc[rb][cb][3][1] += (av).w * (bv).y; \
                acc[rb][cb][3][2] += (av).w * (bv).z; acc[rb][cb][3][3] += (av).w * (bv).w;
            ACC_TILE(0, 0, a0, b0) ACC_TILE(0, 1, a0, b1)
            ACC_TILE(1, 0, a1, b0) ACC_TILE(1, 1, a1, b1)
        }
        __syncthreads();
    }

    float* Pblk = P + ((size_t)(ks * 2 + tp) * 1024 + m0) * FH;
    #pragma unroll
    for (int rb = 0; rb < 2; ++rb)
        #pragma unroll
        for (int r = 0; r < 4; ++r) {
            const int row = rb * 64 + ty * 4 + r;
            #pragma unroll
            for (int cb = 0; cb < 2; ++cb)
                #pragma unroll
                for (int c = 0; c < 4; ++c) {
                    const int col = n0 + cb * 64 + tx * 4 + c;
                    if (col < FH) Pblk[(size_t)row * FH + col] = acc[rb][cb][r][c];
                }
        }
}

// ---------------------------------------------------------------------------
// k_fit_reduce: Out = tanh(sum_ks P + bias) [+ Ain if RES]
// ---------------------------------------------------------------------------
template<int KSPLIT, bool RES>
__global__ __launch_bounds__(256) void k_fit_reduce(
    const float* __restrict__ P, const float* __restrict__ Bias,
    const float* __restrict__ Ain, float* __restrict__ Out)
{
    const int idx = blockIdx.x * 256 + threadIdx.x;
    if (idx >= 2 * 1024 * FH) return;
    const int tp  = idx / (1024 * FH);
    const int rem = idx - tp * (1024 * FH);
    const int col = rem % FH;
    float s = 0.f;
    #pragma unroll
    for (int ks = 0; ks < KSPLIT; ++ks)
        s += P[(size_t)(ks * 2 + tp) * 1024 * FH + rem];
    float v = fast_tanh(s + Bias[tp * FH + col]);
    if (RES) v += Ain[idx];
    Out[idx] = v;
}

// ---------------------------------------------------------------------------
// k_out: one wave per atom: out = h . W3 + b3
// ---------------------------------------------------------------------------
__global__ __launch_bounds__(256) void k_out(
    const float* __restrict__ Hin, const float* __restrict__ W3,
    const float* __restrict__ b3, float* __restrict__ out)
{
    const int wave = (int)((blockIdx.x * 256 + threadIdx.x) >> 6);
    const int lane = threadIdx.x & 63;
    const int tp = wave >> 10;
    const int rem = wave & 1023;
    const int b = rem >> 8, n = rem & 255;
    const float* h = Hin + (size_t)wave * FH;
    const float* wv = W3 + tp * FH;
    float s = 0.f;
    for (int k = lane; k < FH; k += 64) s += h[k] * wv[k];
    #pragma unroll
    for (int off = 32; off > 0; off >>= 1) s += __shfl_down(s, off);
    if (lane == 0) out[b * 512 + tp * 256 + n] = s + b3[tp];
}

// ---------------------------------------------------------------------------
extern "C" void kernel_launch(void* const* d_in, const int* in_sizes, int n_in,
                              void* d_out, int out_size, void* d_ws, size_t ws_size,
                              hipStream_t stream)
{
    const float* Ri  = (const float*)d_in[0];
    const float* eW0 = (const float*)d_in[1];
    const float* eB0 = (const float*)d_in[2];
    const float* eW1 = (const float*)d_in[3];
    const float* eB1 = (const float*)d_in[4];
    const float* eW2 = (const float*)d_in[5];
    const float* eB2 = (const float*)d_in[6];
    const float* fW0 = (const float*)d_in[7];
    const float* fb0 = (const float*)d_in[8];
    const float* fW1 = (const float*)d_in[9];
    const float* fb1 = (const float*)d_in[10];
    const float* fW2 = (const float*)d_in[11];
    const float* fb2 = (const float*)d_in[12];
    const float* fW3 = (const float*)d_in[13];
    const float* fb3 = (const float*)d_in[14];

    const size_t TBLF = (size_t)4 * NK * 100;       // table floats
    const size_t DRF  = (size_t)2 * 1024 * FIT_IN;
    const size_t HF   = (size_t)2 * 1024 * FH;

    // choose layer-0 KSPLIT by available workspace
    auto need = [&](int ks0, int ksf) -> size_t {
        size_t pf = (size_t)((ks0 > ksf ? ks0 : ksf)) * HF;
        return (TBLF + DRF + pf + 2 * HF) * sizeof(float);
    };
    int KS0, KSF;
    if      (ws_size >= need(16, 8)) { KS0 = 16; KSF = 8; }
    else if (ws_size >= need(8, 8))  { KS0 = 8;  KSF = 8; }
    else                             { KS0 = 4;  KSF = 4; }

    float* T  = (float*)d_ws;
    float* DR = T + TBLF;
    float* P  = DR + DRF;
    const size_t PF = (size_t)((KS0 > KSF ? KS0 : KSF)) * HF;
    float* hA = P + PF;
    float* hB = hA + HF;

    const int NOUT = 2 * 1024 * FH;
    const int RBLK = (NOUT + 255) / 256;

    k_table<<<dim3(NK / 128, 4), dim3(128), 0, stream>>>(eW0, eB0, eW1, eB1, eW2, eB2, T);
    k_xyz<<<dim3(2048), dim3(256), 0, stream>>>(Ri, T, DR);

    if (KS0 == 16)
        k_fit_part<FIT_IN, 16><<<dim3(2, 8, 32), dim3(256), 0, stream>>>(DR, fW0, P);
    else if (KS0 == 8)
        k_fit_part<FIT_IN, 8><<<dim3(2, 8, 16), dim3(256), 0, stream>>>(DR, fW0, P);
    else
        k_fit_part<FIT_IN, 4><<<dim3(2, 8, 8), dim3(256), 0, stream>>>(DR, fW0, P);

    if (KS0 == 16)
        k_fit_reduce<16, false><<<dim3(RBLK), dim3(256), 0, stream>>>(P, fb0, nullptr, hA);
    else if (KS0 == 8)
        k_fit_reduce<8, false><<<dim3(RBLK), dim3(256), 0, stream>>>(P, fb0, nullptr, hA);
    else
        k_fit_reduce<4, false><<<dim3(RBLK), dim3(256), 0, stream>>>(P, fb0, nullptr, hA);

    if (KSF == 8) {
        k_fit_part<FH, 8><<<dim3(2, 8, 16), dim3(256), 0, stream>>>(hA, fW1, P);
        k_fit_reduce<8, true><<<dim3(RBLK), dim3(256), 0, stream>>>(P, fb1, hA, hB);
        k_fit_part<FH, 8><<<dim3(2, 8, 16), dim3(256), 0, stream>>>(hB, fW2, P);
        k_fit_reduce<8, true><<<dim3(RBLK), dim3(256), 0, stream>>>(P, fb2, hB, hA);
    } else {
        k_fit_part<FH, 4><<<dim3(2, 8, 8), dim3(256), 0, stream>>>(hA, fW1, P);
        k_fit_reduce<4, true><<<dim3(RBLK), dim3(256), 0, stream>>>(P, fb1, hA, hB);
        k_fit_part<FH, 4><<<dim3(2, 8, 8), dim3(256), 0, stream>>>(hB, fW2, P);
        k_fit_reduce<4, true><<<dim3(RBLK), dim3(256), 0, stream>>>(P, fb2, hB, hA);
    }

    k_out<<<dim3(512), dim3(256), 0, stream>>>(hA, fW3, fb3, (float*)d_out);
}

// Round 6
// 248.174 us; speedup vs baseline: 3.9381x; 1.8614x over previous
//
#include <hip/hip_runtime.h>
#include <hip/hip_bf16.h>

#define FH 240
#define FIT_IN 1600
#define NK 2048            // table knots per e
#define TLO -16.0f
#define TINVH 64.0f        // knots per unit S (h = 1/64)

__device__ __forceinline__ float fast_tanh(float x) {
    float e2 = __builtin_amdgcn_exp2f(x * 2.8853900817779268f);
    return 1.0f - 2.0f * __builtin_amdgcn_rcpf(e2 + 1.0f);
}

#define FMA_ROW(r, s) \
    acc[r][0] += (s) * b0.x; acc[r][1] += (s) * b0.y; \
    acc[r][2] += (s) * b0.z; acc[r][3] += (s) * b0.w; \
    acc[r][4] += (s) * b1.x; acc[r][5] += (s) * b1.y; \
    acc[r][6] += (s) * b1.z; acc[r][7] += (s) * b1.w;

// ---------------------------------------------------------------------------
// k_table: piecewise-linear table T[e][knot][100] of the embedding MLP.
// LDS-tiled GEMM structure (R4 k_emb layout): weights staged once, knots = M.
// 128 knots per block, 256 threads, 4x8 register tiles, b128 both operands.
// ---------------------------------------------------------------------------
#define TOFF_W0   0       // 25 (pad 28)
#define TOFF_B0   28      // 25 (pad 28)
#define TOFF_B1   56      // 50 (pad 52)
#define TOFF_B2   108     // 100
#define TOFF_W1   208     // 25 x 52
#define TOFF_W2   1508    // 50 x 104 (two 52-aligned halves)
#define TOFF_H0T  6708    // 25 x 132  [k][m]
#define TOFF_H1T  10008   // 50 x 132  [k][m]
#define TSMEM     16608   // 66432 B -> 2 blocks/CU

__global__ __launch_bounds__(256) void k_table(
    const float* __restrict__ eW0, const float* __restrict__ eB0,
    const float* __restrict__ eW1, const float* __restrict__ eB1,
    const float* __restrict__ eW2, const float* __restrict__ eB2,
    float* __restrict__ T)
{
    __shared__ float sm[TSMEM];

    const int t    = threadIdx.x;
    const int w    = t >> 6;
    const int lane = t & 63;
    const int mi   = lane & 7;
    const int gi   = lane >> 3;
    const int mrow = w * 32 + mi * 4;

    const int e  = blockIdx.y;
    const int k0 = blockIdx.x * 128;

    // ---- stage weights into LDS (coalesced) ----
    for (int idx = t; idx < 1250; idx += 256) {
        int k = idx / 50, g = idx - k * 50;
        sm[TOFF_W1 + k * 52 + g] = eW1[e * 1250 + idx];
    }
    for (int idx = t; idx < 5000; idx += 256) {
        int k = idx / 100, r = idx - k * 100;
        int half = r / 50, g = r - half * 50;
        sm[TOFF_W2 + k * 104 + half * 52 + g] = eW2[e * 5000 + idx];
    }
    if (t < 25)       { sm[TOFF_W0 + t] = eW0[e * 25 + t]; sm[TOFF_B0 + t] = eB0[e * 25 + t]; }
    else if (t < 75)  { sm[TOFF_B1 + (t - 25)] = eB1[e * 50 + (t - 25)]; }
    else if (t < 175) { sm[TOFF_B2 + (t - 75)] = eB2[e * 100 + (t - 75)]; }
    __syncthreads();

    // ---- layer 1: h0 transposed [k][m] ----
    if (t < 128) {
        const float S = TLO + (float)(k0 + t) * (1.0f / TINVH);
        #pragma unroll
        for (int k = 0; k < 25; ++k)
            sm[TOFF_H0T + k * 132 + t] = fast_tanh(S * sm[TOFF_W0 + k] + sm[TOFF_B0 + k]);
    }
    __syncthreads();

    // ---- GEMM1: M=128 N=50 K=25 ----
    {
        float acc[4][8];
        #pragma unroll
        for (int r = 0; r < 4; ++r)
            #pragma unroll
            for (int c = 0; c < 8; ++c) acc[r][c] = 0.f;

        #pragma unroll 5
        for (int k = 0; k < 25; ++k) {
            const float4 av = *(const float4*)&sm[TOFF_H0T + k * 132 + mrow];
            const float4 b0 = *(const float4*)&sm[TOFF_W1 + k * 52 + gi * 8];
            const float4 b1 = *(const float4*)&sm[TOFF_W1 + k * 52 + gi * 8 + 4];
            FMA_ROW(0, av.x) FMA_ROW(1, av.y) FMA_ROW(2, av.z) FMA_ROW(3, av.w)
        }
        #pragma unroll
        for (int c = 0; c < 8; ++c) {
            const int g = gi * 8 + c;
            if (g < 50) {
                const int gm = (g < 25) ? g : g - 25;
                const float4 h0r = *(const float4*)&sm[TOFF_H0T + gm * 132 + mrow];
                const float bias = sm[TOFF_B1 + g];
                float4 o;
                o.x = fast_tanh(acc[0][c] + bias) + h0r.x;
                o.y = fast_tanh(acc[1][c] + bias) + h0r.y;
                o.z = fast_tanh(acc[2][c] + bias) + h0r.z;
                o.w = fast_tanh(acc[3][c] + bias) + h0r.w;
                *(float4*)&sm[TOFF_H1T + g * 132 + mrow] = o;
            }
        }
    }
    __syncthreads();

    // ---- GEMM2 halves: G = tanh(h1@W2+b2)+h1 -> T[e][knot][g] ----
    for (int half = 0; half < 2; ++half) {
        float acc[4][8];
        #pragma unroll
        for (int r = 0; r < 4; ++r)
            #pragma unroll
            for (int c = 0; c < 8; ++c) acc[r][c] = 0.f;

        #pragma unroll 5
        for (int k = 0; k < 50; ++k) {
            const float4 av = *(const float4*)&sm[TOFF_H1T + k * 132 + mrow];
            const float4 b0 = *(const float4*)&sm[TOFF_W2 + k * 104 + half * 52 + gi * 8];
            const float4 b1 = *(const float4*)&sm[TOFF_W2 + k * 104 + half * 52 + gi * 8 + 4];
            FMA_ROW(0, av.x) FMA_ROW(1, av.y) FMA_ROW(2, av.z) FMA_ROW(3, av.w)
        }
        #pragma unroll
        for (int c = 0; c < 8; ++c) {
            const int g = gi * 8 + c;
            if (g < 50) {
                const float4 h1r = *(const float4*)&sm[TOFF_H1T + g * 132 + mrow];
                const float bias = sm[TOFF_B2 + half * 50 + g];
                float* out = T + ((size_t)e * NK + k0 + mrow) * 100 + half * 50 + g;
                out[0]   = fast_tanh(acc[0][c] + bias) + h1r.x;
                out[100] = fast_tanh(acc[1][c] + bias) + h1r.y;
                out[200] = fast_tanh(acc[2][c] + bias) + h1r.z;
                out[300] = fast_tanh(acc[3][c] + bias) + h1r.w;
            }
        }
    }
}

// ---------------------------------------------------------------------------
// k_xyz: per atom: gather+lerp G from table, reduce xyz[c][g], emit DR.
// ---------------------------------------------------------------------------
__global__ __launch_bounds__(256) void k_xyz(
    const float* __restrict__ Ri, const float* __restrict__ T,
    float* __restrict__ DRws)
{
    __shared__ float4 sR[256];
    __shared__ float  sF[256];
    __shared__ int    sI[256];
    __shared__ float  sXYZ[400];

    const int t   = threadIdx.x;
    const int blk = blockIdx.x;          // 0..2047
    const int b   = blk >> 9;
    const int i   = (blk >> 8) & 1;
    const int n   = blk & 255;

    for (int idx = t; idx < 400; idx += 256) sXYZ[idx] = 0.f;

    {
        const int jj = t >> 7, m = t & 127;
        const size_t row = ((size_t)(b * 512 + i * 256 + n)) * 256 + jj * 128 + m;
        const float4 r = *(const float4*)(Ri + row * 4);
        sR[t] = r;
        float u = (r.x - TLO) * TINVH;
        int ii = (int)u;
        ii = (ii < 0) ? 0 : ((ii > NK - 2) ? NK - 2 : ii);
        sI[t] = ii;
        sF[t] = u - (float)ii;
    }
    __syncthreads();

    const int jj = t >> 7;
    const int g  = t & 127;
    if (g < 100) {
        const float* Te = T + ((size_t)(i * 2 + jj)) * NK * 100 + g;
        float a0 = 0.f, a1 = 0.f, a2 = 0.f, a3 = 0.f;
        #pragma unroll 4
        for (int m = 0; m < 128; ++m) {
            const int s = jj * 128 + m;
            const float4 R = sR[s];
            const float  f = sF[s];
            const float* p = Te + (size_t)sI[s] * 100;
            const float v0 = p[0], v1 = p[100];
            const float G = v0 + f * (v1 - v0);
            a0 += R.x * G; a1 += R.y * G; a2 += R.z * G; a3 += R.w * G;
        }
        atomicAdd(&sXYZ[g],       a0);
        atomicAdd(&sXYZ[100 + g], a1);
        atomicAdd(&sXYZ[200 + g], a2);
        atomicAdd(&sXYZ[300 + g], a3);
    }
    __syncthreads();

    const float inv = 1.0f / 65536.0f;
    float* dr = DRws + (((size_t)i * 4 + b) * 256 + n) * FIT_IN;
    for (int idx = t; idx < FIT_IN; idx += 256) {
        const int gg = idx >> 4, h = idx & 15;
        dr[idx] = (sXYZ[gg] * sXYZ[h] + sXYZ[100 + gg] * sXYZ[100 + h]
                 + sXYZ[200 + gg] * sXYZ[200 + h] + sXYZ[300 + gg] * sXYZ[300 + h]) * inv;
    }
}

// ---------------------------------------------------------------------------
// k_fit_part: partial GEMM over one K-slice. 128x128 tile, 8x8 per lane.
// ---------------------------------------------------------------------------
template<int K, int KSPLIT>
__global__ __launch_bounds__(256) void k_fit_part(
    const float* __restrict__ A, const float* __restrict__ W,
    float* __restrict__ P)
{
    constexpr int CHUNK = (K + KSPLIT - 1) / KSPLIT;
    __shared__ __attribute__((aligned(16))) float sA[16 * 132];
    __shared__ __attribute__((aligned(16))) float sB[16 * 132];

    const int t  = threadIdx.x;
    const int tx = t & 15, ty = t >> 4;
    const int n0 = blockIdx.x * 128;
    const int m0 = blockIdx.y * 128;
    const int tp = blockIdx.z & 1;
    const int ks = blockIdx.z >> 1;
    const int kbeg = ks * CHUNK;
    const int kend = (kbeg + CHUNK < K) ? (kbeg + CHUNK) : K;

    const float* Ablk = A + ((size_t)tp * 1024 + m0) * K;
    const float* Wblk = W + (size_t)tp * K * FH;

    float acc[2][2][4][4];
    #pragma unroll
    for (int rb = 0; rb < 2; ++rb)
        #pragma unroll
        for (int cb = 0; cb < 2; ++cb)
            #pragma unroll
            for (int r = 0; r < 4; ++r)
                #pragma unroll
                for (int c = 0; c < 4; ++c) acc[rb][cb][r][c] = 0.f;

    for (int k0 = kbeg; k0 < kend; k0 += 16) {
        for (int idx = t; idx < 2048; idx += 256) {
            const int m = idx >> 4, kk = idx & 15;
            const int k = k0 + kk;
            sA[kk * 132 + m] = (k < kend) ? Ablk[(size_t)m * K + k] : 0.f;
        }
        for (int idx = t; idx < 2048; idx += 256) {
            const int nn = idx & 127, kk = idx >> 7;
            const int k = k0 + kk, col = n0 + nn;
            sB[kk * 132 + nn] = (k < kend && col < FH) ? Wblk[(size_t)k * FH + col] : 0.f;
        }
        __syncthreads();
        #pragma unroll
        for (int kk = 0; kk < 16; ++kk) {
            const float4 a0 = *(const float4*)&sA[kk * 132 + ty * 4];
            const float4 a1 = *(const float4*)&sA[kk * 132 + ty * 4 + 64];
            const float4 b0 = *(const float4*)&sB[kk * 132 + tx * 4];
            const float4 b1 = *(const float4*)&sB[kk * 132 + tx * 4 + 64];
            #define ACC_TILE(rb, cb, av, bv) \
                acc[rb][cb][0][0] += (av).x * (bv).x; acc[rb][cb][0][1] += (av).x * (bv).y; \
                acc[rb][cb][0][2] += (av).x * (bv).z; acc[rb][cb][0][3] += (av).x * (bv).w; \
                acc[rb][cb][1][0] += (av).y * (bv).x; acc[rb][cb][1][1] += (av).y * (bv).y; \
                acc[rb][cb][1][2] += (av).y * (bv).z; acc[rb][cb][1][3] += (av).y * (bv).w; \
                acc[rb][cb][2][0] += (av).z * (bv).x; acc[rb][cb][2][1] += (av).z * (bv).y; \
                acc[rb][cb][2][2] += (av).z * (bv).z; acc[rb][cb][2][3] += (av).z * (bv).w; \
                acc[rb][cb][3][0] += (av).w * (bv).x; acc[rb][cb][3][1] += (av).w * (bv).y; \
                acc[rb][cb][3][2] += (av).w * (bv).z; acc[rb][cb][3][3] += (av).w * (bv).w;
            ACC_TILE(0, 0, a0, b0) ACC_TILE(0, 1, a0, b1)
            ACC_TILE(1, 0, a1, b0) ACC_TILE(1, 1, a1, b1)
        }
        __syncthreads();
    }

    float* Pblk = P + ((size_t)(ks * 2 + tp) * 1024 + m0) * FH;
    #pragma unroll
    for (int rb = 0; rb < 2; ++rb)
        #pragma unroll
        for (int r = 0; r < 4; ++r) {
            const int row = rb * 64 + ty * 4 + r;
            #pragma unroll
            for (int cb = 0; cb < 2; ++cb)
                #pragma unroll
                for (int c = 0; c < 4; ++c) {
                    const int col = n0 + cb * 64 + tx * 4 + c;
                    if (col < FH) Pblk[(size_t)row * FH + col] = acc[rb][cb][r][c];
                }
        }
}

// ---------------------------------------------------------------------------
// k_fit_reduce: Out = tanh(sum_ks P + bias) [+ Ain if RES]
// ---------------------------------------------------------------------------
template<int KSPLIT, bool RES>
__global__ __launch_bounds__(256) void k_fit_reduce(
    const float* __restrict__ P, const float* __restrict__ Bias,
    const float* __restrict__ Ain, float* __restrict__ Out)
{
    const int idx = blockIdx.x * 256 + threadIdx.x;
    if (idx >= 2 * 1024 * FH) return;
    const int tp  = idx / (1024 * FH);
    const int rem = idx - tp * (1024 * FH);
    const int col = rem % FH;
    float s = 0.f;
    #pragma unroll
    for (int ks = 0; ks < KSPLIT; ++ks)
        s += P[(size_t)(ks * 2 + tp) * 1024 * FH + rem];
    float v = fast_tanh(s + Bias[tp * FH + col]);
    if (RES) v += Ain[idx];
    Out[idx] = v;
}

// ---------------------------------------------------------------------------
// k_out: one wave per atom: out = h . W3 + b3
// ---------------------------------------------------------------------------
__global__ __launch_bounds__(256) void k_out(
    const float* __restrict__ Hin, const float* __restrict__ W3,
    const float* __restrict__ b3, float* __restrict__ out)
{
    const int wave = (int)((blockIdx.x * 256 + threadIdx.x) >> 6);
    const int lane = threadIdx.x & 63;
    const int tp = wave >> 10;
    const int rem = wave & 1023;
    const int b = rem >> 8, n = rem & 255;
    const float* h = Hin + (size_t)wave * FH;
    const float* wv = W3 + tp * FH;
    float s = 0.f;
    for (int k = lane; k < FH; k += 64) s += h[k] * wv[k];
    #pragma unroll
    for (int off = 32; off > 0; off >>= 1) s += __shfl_down(s, off);
    if (lane == 0) out[b * 512 + tp * 256 + n] = s + b3[tp];
}

// ---------------------------------------------------------------------------
extern "C" void kernel_launch(void* const* d_in, const int* in_sizes, int n_in,
                              void* d_out, int out_size, void* d_ws, size_t ws_size,
                              hipStream_t stream)
{
    const float* Ri  = (const float*)d_in[0];
    const float* eW0 = (const float*)d_in[1];
    const float* eB0 = (const float*)d_in[2];
    const float* eW1 = (const float*)d_in[3];
    const float* eB1 = (const float*)d_in[4];
    const float* eW2 = (const float*)d_in[5];
    const float* eB2 = (const float*)d_in[6];
    const float* fW0 = (const float*)d_in[7];
    const float* fb0 = (const float*)d_in[8];
    const float* fW1 = (const float*)d_in[9];
    const float* fb1 = (const float*)d_in[10];
    const float* fW2 = (const float*)d_in[11];
    const float* fb2 = (const float*)d_in[12];
    const float* fW3 = (const float*)d_in[13];
    const float* fb3 = (const float*)d_in[14];

    const size_t TBLF = (size_t)4 * NK * 100;
    const size_t DRF  = (size_t)2 * 1024 * FIT_IN;
    const size_t HF   = (size_t)2 * 1024 * FH;

    auto need = [&](int ks0, int ksf) -> size_t {
        size_t pf = (size_t)((ks0 > ksf ? ks0 : ksf)) * HF;
        return (TBLF + DRF + pf + 2 * HF) * sizeof(float);
    };
    int KS0, KSF;
    if      (ws_size >= need(16, 8)) { KS0 = 16; KSF = 8; }
    else if (ws_size >= need(8, 8))  { KS0 = 8;  KSF = 8; }
    else                             { KS0 = 4;  KSF = 4; }

    float* T  = (float*)d_ws;
    float* DR = T + TBLF;
    float* P  = DR + DRF;
    const size_t PF = (size_t)((KS0 > KSF ? KS0 : KSF)) * HF;
    float* hA = P + PF;
    float* hB = hA + HF;

    const int NOUT = 2 * 1024 * FH;
    const int RBLK = (NOUT + 255) / 256;

    k_table<<<dim3(NK / 128, 4), dim3(256), 0, stream>>>(eW0, eB0, eW1, eB1, eW2, eB2, T);
    k_xyz<<<dim3(2048), dim3(256), 0, stream>>>(Ri, T, DR);

    if (KS0 == 16)
        k_fit_part<FIT_IN, 16><<<dim3(2, 8, 32), dim3(256), 0, stream>>>(DR, fW0, P);
    else if (KS0 == 8)
        k_fit_part<FIT_IN, 8><<<dim3(2, 8, 16), dim3(256), 0, stream>>>(DR, fW0, P);
    else
        k_fit_part<FIT_IN, 4><<<dim3(2, 8, 8), dim3(256), 0, stream>>>(DR, fW0, P);

    if (KS0 == 16)
        k_fit_reduce<16, false><<<dim3(RBLK), dim3(256), 0, stream>>>(P, fb0, nullptr, hA);
    else if (KS0 == 8)
        k_fit_reduce<8, false><<<dim3(RBLK), dim3(256), 0, stream>>>(P, fb0, nullptr, hA);
    else
        k_fit_reduce<4, false><<<dim3(RBLK), dim3(256), 0, stream>>>(P, fb0, nullptr, hA);

    if (KSF == 8) {
        k_fit_part<FH, 8><<<dim3(2, 8, 16), dim3(256), 0, stream>>>(hA, fW1, P);
        k_fit_reduce<8, true><<<dim3(RBLK), dim3(256), 0, stream>>>(P, fb1, hA, hB);
        k_fit_part<FH, 8><<<dim3(2, 8, 16), dim3(256), 0, stream>>>(hB, fW2, P);
        k_fit_reduce<8, true><<<dim3(RBLK), dim3(256), 0, stream>>>(P, fb2, hB, hA);
    } else {
        k_fit_part<FH, 4><<<dim3(2, 8, 8), dim3(256), 0, stream>>>(hA, fW1, P);
        k_fit_reduce<4, true><<<dim3(RBLK), dim3(256), 0, stream>>>(P, fb1, hA, hB);
        k_fit_part<FH, 4><<<dim3(2, 8, 8), dim3(256), 0, stream>>>(hB, fW2, P);
        k_fit_reduce<4, true><<<dim3(RBLK), dim3(256), 0, stream>>>(P, fb2, hB, hA);
    }

    k_out<<<dim3(512), dim3(256), 0, stream>>>(hA, fW3, fb3, (float*)d_out);
}

// Round 7
// 196.916 us; speedup vs baseline: 4.9632x; 1.2603x over previous
//
#include <hip/hip_runtime.h>
#include <hip/hip_bf16.h>

#define FH 240
#define FIT_IN 1600
#define NK 2048            // table knots per e
#define TLO -16.0f
#define TINVH 64.0f        // knots per unit S (h = 1/64)

typedef _Float16 h8 __attribute__((ext_vector_type(8)));
typedef float f4v __attribute__((ext_vector_type(4)));

__device__ __forceinline__ float fast_tanh(float x) {
    float e2 = __builtin_amdgcn_exp2f(x * 2.8853900817779268f);
    return 1.0f - 2.0f * __builtin_amdgcn_rcpf(e2 + 1.0f);
}

#define FMA_ROW(r, s) \
    acc[r][0] += (s) * b0.x; acc[r][1] += (s) * b0.y; \
    acc[r][2] += (s) * b0.z; acc[r][3] += (s) * b0.w; \
    acc[r][4] += (s) * b1.x; acc[r][5] += (s) * b1.y; \
    acc[r][6] += (s) * b1.z; acc[r][7] += (s) * b1.w;

// ---------------------------------------------------------------------------
// k_table: piecewise-linear table T[e][knot][100] of the embedding MLP.
// (unchanged from R6 — LDS-tiled GEMM, 128 knots/block)
// ---------------------------------------------------------------------------
#define TOFF_W0   0
#define TOFF_B0   28
#define TOFF_B1   56
#define TOFF_B2   108
#define TOFF_W1   208
#define TOFF_W2   1508
#define TOFF_H0T  6708
#define TOFF_H1T  10008
#define TSMEM     16608

__global__ __launch_bounds__(256) void k_table(
    const float* __restrict__ eW0, const float* __restrict__ eB0,
    const float* __restrict__ eW1, const float* __restrict__ eB1,
    const float* __restrict__ eW2, const float* __restrict__ eB2,
    float* __restrict__ T)
{
    __shared__ float sm[TSMEM];

    const int t    = threadIdx.x;
    const int w    = t >> 6;
    const int lane = t & 63;
    const int mi   = lane & 7;
    const int gi   = lane >> 3;
    const int mrow = w * 32 + mi * 4;

    const int e  = blockIdx.y;
    const int k0 = blockIdx.x * 128;

    for (int idx = t; idx < 1250; idx += 256) {
        int k = idx / 50, g = idx - k * 50;
        sm[TOFF_W1 + k * 52 + g] = eW1[e * 1250 + idx];
    }
    for (int idx = t; idx < 5000; idx += 256) {
        int k = idx / 100, r = idx - k * 100;
        int half = r / 50, g = r - half * 50;
        sm[TOFF_W2 + k * 104 + half * 52 + g] = eW2[e * 5000 + idx];
    }
    if (t < 25)       { sm[TOFF_W0 + t] = eW0[e * 25 + t]; sm[TOFF_B0 + t] = eB0[e * 25 + t]; }
    else if (t < 75)  { sm[TOFF_B1 + (t - 25)] = eB1[e * 50 + (t - 25)]; }
    else if (t < 175) { sm[TOFF_B2 + (t - 75)] = eB2[e * 100 + (t - 75)]; }
    __syncthreads();

    if (t < 128) {
        const float S = TLO + (float)(k0 + t) * (1.0f / TINVH);
        #pragma unroll
        for (int k = 0; k < 25; ++k)
            sm[TOFF_H0T + k * 132 + t] = fast_tanh(S * sm[TOFF_W0 + k] + sm[TOFF_B0 + k]);
    }
    __syncthreads();

    {
        float acc[4][8];
        #pragma unroll
        for (int r = 0; r < 4; ++r)
            #pragma unroll
            for (int c = 0; c < 8; ++c) acc[r][c] = 0.f;

        #pragma unroll 5
        for (int k = 0; k < 25; ++k) {
            const float4 av = *(const float4*)&sm[TOFF_H0T + k * 132 + mrow];
            const float4 b0 = *(const float4*)&sm[TOFF_W1 + k * 52 + gi * 8];
            const float4 b1 = *(const float4*)&sm[TOFF_W1 + k * 52 + gi * 8 + 4];
            FMA_ROW(0, av.x) FMA_ROW(1, av.y) FMA_ROW(2, av.z) FMA_ROW(3, av.w)
        }
        #pragma unroll
        for (int c = 0; c < 8; ++c) {
            const int g = gi * 8 + c;
            if (g < 50) {
                const int gm = (g < 25) ? g : g - 25;
                const float4 h0r = *(const float4*)&sm[TOFF_H0T + gm * 132 + mrow];
                const float bias = sm[TOFF_B1 + g];
                float4 o;
                o.x = fast_tanh(acc[0][c] + bias) + h0r.x;
                o.y = fast_tanh(acc[1][c] + bias) + h0r.y;
                o.z = fast_tanh(acc[2][c] + bias) + h0r.z;
                o.w = fast_tanh(acc[3][c] + bias) + h0r.w;
                *(float4*)&sm[TOFF_H1T + g * 132 + mrow] = o;
            }
        }
    }
    __syncthreads();

    for (int half = 0; half < 2; ++half) {
        float acc[4][8];
        #pragma unroll
        for (int r = 0; r < 4; ++r)
            #pragma unroll
            for (int c = 0; c < 8; ++c) acc[r][c] = 0.f;

        #pragma unroll 5
        for (int k = 0; k < 50; ++k) {
            const float4 av = *(const float4*)&sm[TOFF_H1T + k * 132 + mrow];
            const float4 b0 = *(const float4*)&sm[TOFF_W2 + k * 104 + half * 52 + gi * 8];
            const float4 b1 = *(const float4*)&sm[TOFF_W2 + k * 104 + half * 52 + gi * 8 + 4];
            FMA_ROW(0, av.x) FMA_ROW(1, av.y) FMA_ROW(2, av.z) FMA_ROW(3, av.w)
        }
        #pragma unroll
        for (int c = 0; c < 8; ++c) {
            const int g = gi * 8 + c;
            if (g < 50) {
                const float4 h1r = *(const float4*)&sm[TOFF_H1T + g * 132 + mrow];
                const float bias = sm[TOFF_B2 + half * 50 + g];
                float* out = T + ((size_t)e * NK + k0 + mrow) * 100 + half * 50 + g;
                out[0]   = fast_tanh(acc[0][c] + bias) + h1r.x;
                out[100] = fast_tanh(acc[1][c] + bias) + h1r.y;
                out[200] = fast_tanh(acc[2][c] + bias) + h1r.z;
                out[300] = fast_tanh(acc[3][c] + bias) + h1r.w;
            }
        }
    }
}

// ---------------------------------------------------------------------------
// k_cvt: f32 weights -> f16 TRANSPOSED WT[tp][n][k] for the three fit layers.
// ---------------------------------------------------------------------------
__global__ __launch_bounds__(256) void k_cvt(
    const float* __restrict__ fW0, const float* __restrict__ fW1,
    const float* __restrict__ fW2,
    _Float16* __restrict__ W0T, _Float16* __restrict__ W1T,
    _Float16* __restrict__ W2T)
{
    const int total = 768000 + 115200 + 115200;
    for (int idx = blockIdx.x * 256 + threadIdx.x; idx < total; idx += gridDim.x * 256) {
        if (idx < 768000) {
            const int tp = idx / 384000, r = idx - tp * 384000;
            const int n = r / 1600, k = r - n * 1600;
            W0T[idx] = (_Float16)fW0[tp * 384000 + k * 240 + n];
        } else if (idx < 883200) {
            const int j = idx - 768000;
            const int tp = j / 57600, r = j - tp * 57600;
            const int n = r / 240, k = r - n * 240;
            W1T[j] = (_Float16)fW1[tp * 57600 + k * 240 + n];
        } else {
            const int j = idx - 883200;
            const int tp = j / 57600, r = j - tp * 57600;
            const int n = r / 240, k = r - n * 240;
            W2T[j] = (_Float16)fW2[tp * 57600 + k * 240 + n];
        }
    }
}

// ---------------------------------------------------------------------------
// k_xyz: per atom: gather+lerp G from table, reduce xyz[c][g], emit DR (f16).
// ---------------------------------------------------------------------------
__global__ __launch_bounds__(256) void k_xyz(
    const float* __restrict__ Ri, const float* __restrict__ T,
    _Float16* __restrict__ DRh)
{
    __shared__ float4 sR[256];
    __shared__ float  sF[256];
    __shared__ int    sI[256];
    __shared__ float  sXYZ[400];

    const int t   = threadIdx.x;
    const int blk = blockIdx.x;          // 0..2047
    const int b   = blk >> 9;
    const int i   = (blk >> 8) & 1;
    const int n   = blk & 255;

    for (int idx = t; idx < 400; idx += 256) sXYZ[idx] = 0.f;

    {
        const int jj = t >> 7, m = t & 127;
        const size_t row = ((size_t)(b * 512 + i * 256 + n)) * 256 + jj * 128 + m;
        const float4 r = *(const float4*)(Ri + row * 4);
        sR[t] = r;
        float u = (r.x - TLO) * TINVH;
        int ii = (int)u;
        ii = (ii < 0) ? 0 : ((ii > NK - 2) ? NK - 2 : ii);
        sI[t] = ii;
        sF[t] = u - (float)ii;
    }
    __syncthreads();

    const int jj = t >> 7;
    const int g  = t & 127;
    if (g < 100) {
        const float* Te = T + ((size_t)(i * 2 + jj)) * NK * 100 + g;
        float a0 = 0.f, a1 = 0.f, a2 = 0.f, a3 = 0.f;
        #pragma unroll 4
        for (int m = 0; m < 128; ++m) {
            const int s = jj * 128 + m;
            const float4 R = sR[s];
            const float  f = sF[s];
            const float* p = Te + (size_t)sI[s] * 100;
            const float v0 = p[0], v1 = p[100];
            const float G = v0 + f * (v1 - v0);
            a0 += R.x * G; a1 += R.y * G; a2 += R.z * G; a3 += R.w * G;
        }
        atomicAdd(&sXYZ[g],       a0);
        atomicAdd(&sXYZ[100 + g], a1);
        atomicAdd(&sXYZ[200 + g], a2);
        atomicAdd(&sXYZ[300 + g], a3);
    }
    __syncthreads();

    const float inv = 1.0f / 65536.0f;
    _Float16* dr = DRh + (((size_t)i * 4 + b) * 256 + n) * FIT_IN;
    for (int q = t; q < 400; q += 256) {
        const int gg = q >> 2, h0 = (q & 3) * 4;
        ushort4 pk;
        _Float16* ph = (_Float16*)&pk;
        #pragma unroll
        for (int r = 0; r < 4; ++r) {
            const int h = h0 + r;
            const float v = (sXYZ[gg] * sXYZ[h] + sXYZ[100 + gg] * sXYZ[100 + h]
                           + sXYZ[200 + gg] * sXYZ[200 + h] + sXYZ[300 + gg] * sXYZ[300 + h]) * inv;
            ph[r] = (_Float16)v;
        }
        *(ushort4*)(dr + gg * 16 + h0) = pk;
    }
}

// ---------------------------------------------------------------------------
// k_fit_mfma: partial GEMM P[ks] = A[rows, kslice] @ W[kslice, 240] via
// f16 MFMA 16x16x32, fp32 acc. A: [2048][K] f16 rowmajor; WT: [2][240][K] f16.
// Block: 64 rows x 240 cols; 4 waves split N (4/4/4/3 n-frags).
// Verified layouts: A[m=lane&15][k=quad*8+j], B[k=quad*8+j][n=lane&15],
// D[row=quad*4+reg][col=lane&15].
// ---------------------------------------------------------------------------
template<int K, int CHUNK>
__global__ __launch_bounds__(256) void k_fit_mfma(
    const _Float16* __restrict__ A, const _Float16* __restrict__ WT,
    float* __restrict__ P)
{
    __shared__ _Float16 sA[64 * 40];     // [m][k] stride 40 (80 B, 16B-aligned)
    __shared__ _Float16 sBT[240 * 40];   // [n][k] stride 40

    const int t    = threadIdx.x;
    const int w    = t >> 6;
    const int lane = t & 63;
    const int ln   = lane & 15;
    const int quad = lane >> 4;

    const int mtile = blockIdx.x;        // 0..31
    const int ks    = blockIdx.y;
    const int row0  = mtile * 64;
    const int tp    = mtile >> 4;
    const int kbeg  = ks * CHUNK;
    const int kend  = (kbeg + CHUNK < K) ? (kbeg + CHUNK) : K;
    const int nf0   = w * 4;
    const int nfrags = (w < 3) ? 4 : 3;

    f4v acc[4][4];
    #pragma unroll
    for (int mf = 0; mf < 4; ++mf)
        #pragma unroll
        for (int nf = 0; nf < 4; ++nf) acc[mf][nf] = (f4v)0.f;

    const _Float16* Ab = A + (size_t)row0 * K;
    const _Float16* Wb = WT + (size_t)tp * 240 * K;

    for (int k0 = kbeg; k0 < kend; k0 += 32) {
        // stage A tile 64x32 (uint2 = 4 f16)
        #pragma unroll
        for (int q = t; q < 512; q += 256) {
            const int m = q >> 3, kq = (q & 7) * 4;
            const int k = k0 + kq;
            uint2 v = make_uint2(0u, 0u);
            if (k < kend) v = *(const uint2*)(Ab + (size_t)m * K + k);
            *(uint2*)&sA[m * 40 + kq] = v;
        }
        // stage W tile 240x32 from transposed WT (coalesced)
        for (int q = t; q < 1920; q += 256) {
            const int n = q >> 3, kq = (q & 7) * 4;
            const int k = k0 + kq;
            uint2 v = make_uint2(0u, 0u);
            if (k < kend) v = *(const uint2*)(Wb + (size_t)n * K + k);
            *(uint2*)&sBT[n * 40 + kq] = v;
        }
        __syncthreads();

        h8 afr[4];
        #pragma unroll
        for (int mf = 0; mf < 4; ++mf)
            afr[mf] = *(const h8*)&sA[(mf * 16 + ln) * 40 + quad * 8];
        #pragma unroll
        for (int nf = 0; nf < 4; ++nf) {
            if (nf < nfrags) {
                const h8 bfr = *(const h8*)&sBT[((nf0 + nf) * 16 + ln) * 40 + quad * 8];
                #pragma unroll
                for (int mf = 0; mf < 4; ++mf)
                    acc[mf][nf] = __builtin_amdgcn_mfma_f32_16x16x32_f16(
                        afr[mf], bfr, acc[mf][nf], 0, 0, 0);
            }
        }
        __syncthreads();
    }

    float* Pb = P + ((size_t)ks * 2048 + row0) * FH;
    #pragma unroll
    for (int nf = 0; nf < 4; ++nf) {
        if (nf < nfrags) {
            const int col = (nf0 + nf) * 16 + ln;
            #pragma unroll
            for (int mf = 0; mf < 4; ++mf)
                #pragma unroll
                for (int r = 0; r < 4; ++r) {
                    const int row = mf * 16 + quad * 4 + r;
                    Pb[(size_t)row * FH + col] = acc[mf][nf][r];
                }
        }
    }
}

// ---------------------------------------------------------------------------
// k_fit_reduce: v = tanh(sum_ks P + bias) [+ Ain]; writes f32 + f16 copies.
// ---------------------------------------------------------------------------
template<int KSPLIT, bool RES>
__global__ __launch_bounds__(256) void k_fit_reduce(
    const float* __restrict__ P, const float* __restrict__ Bias,
    const float* __restrict__ AinF, float* __restrict__ OutF,
    _Float16* __restrict__ OutH)
{
    const int idx = blockIdx.x * 256 + threadIdx.x;
    if (idx >= 2048 * FH) return;
    const int tp  = idx / (1024 * FH);
    const int col = idx % FH;
    float s = 0.f;
    #pragma unroll
    for (int ks = 0; ks < KSPLIT; ++ks)
        s += P[(size_t)ks * 2048 * FH + idx];
    float v = fast_tanh(s + Bias[tp * FH + col]);
    if (RES) v += AinF[idx];
    OutF[idx] = v;
    OutH[idx] = (_Float16)v;
}

// ---------------------------------------------------------------------------
// k_out: one wave per atom: out = h . W3 + b3
// ---------------------------------------------------------------------------
__global__ __launch_bounds__(256) void k_out(
    const float* __restrict__ Hin, const float* __restrict__ W3,
    const float* __restrict__ b3, float* __restrict__ out)
{
    const int wave = (int)((blockIdx.x * 256 + threadIdx.x) >> 6);
    const int lane = threadIdx.x & 63;
    const int tp = wave >> 10;
    const int rem = wave & 1023;
    const int b = rem >> 8, n = rem & 255;
    const float* h = Hin + (size_t)wave * FH;
    const float* wv = W3 + tp * FH;
    float s = 0.f;
    for (int k = lane; k < FH; k += 64) s += h[k] * wv[k];
    #pragma unroll
    for (int off = 32; off > 0; off >>= 1) s += __shfl_down(s, off);
    if (lane == 0) out[b * 512 + tp * 256 + n] = s + b3[tp];
}

// ---------------------------------------------------------------------------
extern "C" void kernel_launch(void* const* d_in, const int* in_sizes, int n_in,
                              void* d_out, int out_size, void* d_ws, size_t ws_size,
                              hipStream_t stream)
{
    const float* Ri  = (const float*)d_in[0];
    const float* eW0 = (const float*)d_in[1];
    const float* eB0 = (const float*)d_in[2];
    const float* eW1 = (const float*)d_in[3];
    const float* eB1 = (const float*)d_in[4];
    const float* eW2 = (const float*)d_in[5];
    const float* eB2 = (const float*)d_in[6];
    const float* fW0 = (const float*)d_in[7];
    const float* fb0 = (const float*)d_in[8];
    const float* fW1 = (const float*)d_in[9];
    const float* fb1 = (const float*)d_in[10];
    const float* fW2 = (const float*)d_in[11];
    const float* fb2 = (const float*)d_in[12];
    const float* fW3 = (const float*)d_in[13];
    const float* fb3 = (const float*)d_in[14];

    // workspace layout (bytes)
    char* p = (char*)d_ws;
    float* T   = (float*)p;                 p += (size_t)4 * NK * 100 * 4;        // 3.28 MB
    float* P   = (float*)p;                 p += (size_t)17 * 2048 * FH * 4;      // 33.4 MB
    float* hA  = (float*)p;                 p += (size_t)2048 * FH * 4;           // 1.97 MB
    float* hB  = (float*)p;                 p += (size_t)2048 * FH * 4;           // 1.97 MB
    _Float16* DRh = (_Float16*)p;           p += (size_t)2048 * FIT_IN * 2;       // 6.55 MB
    _Float16* hAh = (_Float16*)p;           p += (size_t)2048 * FH * 2;           // 0.98 MB
    _Float16* hBh = (_Float16*)p;           p += (size_t)2048 * FH * 2;           // 0.98 MB
    _Float16* W0T = (_Float16*)p;           p += (size_t)768000 * 2;              // 1.54 MB
    _Float16* W1T = (_Float16*)p;           p += (size_t)115200 * 2;
    _Float16* W2T = (_Float16*)p;           p += (size_t)115200 * 2;

    const int RBLK = (2048 * FH + 255) / 256;

    k_cvt<<<dim3(1024), dim3(256), 0, stream>>>(fW0, fW1, fW2, W0T, W1T, W2T);
    k_table<<<dim3(NK / 128, 4), dim3(256), 0, stream>>>(eW0, eB0, eW1, eB1, eW2, eB2, T);
    k_xyz<<<dim3(2048), dim3(256), 0, stream>>>(Ri, T, DRh);

    // layer 0: K=1600, CHUNK=96, KSPLIT=17
    k_fit_mfma<FIT_IN, 96><<<dim3(32, 17), dim3(256), 0, stream>>>(DRh, W0T, P);
    k_fit_reduce<17, false><<<dim3(RBLK), dim3(256), 0, stream>>>(P, fb0, nullptr, hA, hAh);

    // layer 1: K=240, CHUNK=32, KSPLIT=8
    k_fit_mfma<FH, 32><<<dim3(32, 8), dim3(256), 0, stream>>>(hAh, W1T, P);
    k_fit_reduce<8, true><<<dim3(RBLK), dim3(256), 0, stream>>>(P, fb1, hA, hB, hBh);

    // layer 2: K=240, CHUNK=32, KSPLIT=8
    k_fit_mfma<FH, 32><<<dim3(32, 8), dim3(256), 0, stream>>>(hBh, W2T, P);
    k_fit_reduce<8, true><<<dim3(RBLK), dim3(256), 0, stream>>>(P, fb2, hB, hA, hAh);

    k_out<<<dim3(512), dim3(256), 0, stream>>>(hA, fW3, fb3, (float*)d_out);
}